// Round 14
// baseline (53085.736 us; speedup 1.0000x reference)
//
#include <hip/hip_runtime.h>

typedef unsigned short u16;
typedef __bf16 bf16x8 __attribute__((ext_vector_type(8)));
typedef float f32x4 __attribute__((ext_vector_type(4)));
typedef unsigned uint32x4 __attribute__((ext_vector_type(4)));

#define EPSC 1e-6f

// ---------- helpers ----------
__device__ __forceinline__ float b2f(u16 x) { return __uint_as_float(((unsigned)x) << 16); }
__device__ __forceinline__ u16 f2b(float f) {
    unsigned u = __float_as_uint(f);
    unsigned r = (u + 0x7fffu + ((u >> 16) & 1u)) >> 16;
    return (u16)r;
}
__device__ __forceinline__ float softplusf(float x) {
    return fmaxf(x, 0.f) + log1pf(__expf(-fabsf(x)));
}

// coherent (cross-XCD) plain load/store: per-instruction sc0|sc1 policy.
__device__ __forceinline__ void ld_cv16_issue(uint32x4& d, const void* p) {
    asm volatile("global_load_dwordx4 %0, %1, off sc0 sc1"
                 : "=v"(d) : "v"((unsigned long long)p) : "memory");
}
__device__ __forceinline__ unsigned ld_cv4(const void* p) {
    unsigned d;
    asm volatile("global_load_dword %0, %1, off sc0 sc1\n\ts_waitcnt vmcnt(0)"
                 : "=v"(d) : "v"((unsigned long long)p) : "memory");
    return d;
}
__device__ __forceinline__ void wait_vm0() {
    asm volatile("s_waitcnt vmcnt(0)" ::: "memory");
    __builtin_amdgcn_sched_barrier(0);
}
__device__ __forceinline__ void st_cv16(void* p, uint32x4 v) {
    asm volatile("global_store_dwordx4 %0, %1, off sc0 sc1"
                 :: "v"((unsigned long long)p), "v"(v) : "memory");
}
__device__ __forceinline__ void st_cv4(void* p, unsigned v) {
    asm volatile("global_store_dword %0, %1, off sc0 sc1"
                 :: "v"((unsigned long long)p), "v"(v) : "memory");
}

// ---------- conversion / transpose kernels ----------
__global__ void conv_x4(u16* __restrict__ dst, const float* __restrict__ x) {
    size_t i4 = (size_t)blockIdx.x * 256 + threadIdx.x;
    size_t o = i4 * 4;
    int d = (int)(o & 511);
    int b = (int)((o >> 9) & 255);
    int t = (int)(o >> 17);
    float4 v = *(const float4*)(x + ((size_t)b * 256 + t) * 512 + d);
    unsigned p0 = (unsigned)f2b(v.x) | ((unsigned)f2b(v.y) << 16);
    unsigned p1 = (unsigned)f2b(v.z) | ((unsigned)f2b(v.w) << 16);
    *(uint2*)(dst + o) = make_uint2(p0, p1);
}

__global__ void conv_f32_bf16(u16* __restrict__ dst, const float* __restrict__ src, int n) {
    int i = blockIdx.x * 256 + threadIdx.x;
    if (i < n) dst[i] = f2b(src[i]);
}

__global__ void tr_conv(u16* __restrict__ dst, const float* __restrict__ src,
                        int R, int C, int ld) {
    int idx = blockIdx.x * 256 + threadIdx.x;
    if (idx >= R * C) return;
    int c = idx / R, r = idx % R;
    dst[idx] = f2b(src[(size_t)r * ld + c]);
}

// MFMA B-frag layouts: contiguous 1KB per wave B-frag read.
// wcatF: N=2048 (em|es outputs), K=2048 ([h|phi]); per col-tile ct(16): 64 kq x 512
__global__ void conv_fragB(u16* __restrict__ dst, const float* __restrict__ em1,
                           const float* __restrict__ es1) {
    int idx = blockIdx.x * 256 + threadIdx.x;       // 524288 threads
    int col = idx >> 8, kb = idx & 255;
    int k = kb * 8, ct = col >> 4, lr = col & 15, kq = kb >> 2, lk = kb & 3;
    size_t off = ((size_t)ct * 64 + kq) * 512 + lk * 128 + lr * 8;
    const float* src = (col < 1024) ? em1 : es1;
    const int c = (col < 1024) ? col : col - 1024;
#pragma unroll
    for (int j = 0; j < 8; j++)
        dst[off + j] = f2b(src[(size_t)(k + j) * 1024 + c]);
}

// W2 frag: N=128, K=1024; per ct(16): 32 kq x 512
__global__ void conv_fragB2(u16* __restrict__ dst, const float* __restrict__ src) {
    int idx = blockIdx.x * 256 + threadIdx.x;       // 16384 threads
    int col = idx >> 7, kb = idx & 127;
    int k = kb * 8, ct = col >> 4, lr = col & 15, kq = kb >> 2, lk = kb & 3;
    size_t off = ((size_t)ct * 32 + kq) * 512 + lk * 128 + lr * 8;
#pragma unroll
    for (int j = 0; j < 8; j++)
        dst[off + j] = f2b(src[(size_t)(k + j) * 128 + col]);
}

// wihZ frag: 3 gates x N=1024 x K=128; per gate 131072 halves; per ct: 4 kq x 512
__global__ void conv_fragG(u16* __restrict__ dst, const float* __restrict__ gwih) {
    int idx = blockIdx.x * 256 + threadIdx.x;       // 49152 threads
    int gate = idx >> 14, rem = idx & 16383;
    int col = rem >> 4, kb = rem & 15;
    int k = kb * 8, ct = col >> 4, lr = col & 15, kq = kb >> 2, lk = kb & 3;
    size_t off = (size_t)gate * 131072 + ((size_t)ct * 4 + kq) * 512 + lk * 128 + lr * 8;
#pragma unroll
    for (int j = 0; j < 8; j++)
        dst[off + j] = f2b(gwih[(size_t)(1024 + k + j) * 3072 + gate * 1024 + col]);
}

__global__ void init_ctr(unsigned* bar) {
#pragma unroll
    for (int i = 0; i < 4; i++) bar[threadIdx.x + i * 256] = 0u;
}

// ---------- generic 128x128 bf16 MFMA GEMM (phase A/C) ----------
enum { EPI_PARTIAL = 0, EPI_BF16_RELU = 1, EPI_BF16_NONE = 2,
       EPI_F32_RELU = 3, EPI_F32_SP = 4, EPI_F32_SIG = 5 };

template <int EPI>
__global__ __launch_bounds__(256)
void gemm128(const u16* __restrict__ A0, const u16* __restrict__ A1,
             int lda0, int lda1, int kSplit,
             const u16* __restrict__ Wt, int ldw,
             const float* __restrict__ bias,
             u16* __restrict__ Cb, float* __restrict__ Cf,
             int M, int N, int K, int kChunk) {
    __shared__ __align__(16) u16 As[128 * 72];
    __shared__ __align__(16) u16 Bs[128 * 72];
    const int tid = threadIdx.x;
    const int wid = tid >> 6, lane = tid & 63;
    const int wm = wid >> 1, wn = wid & 1;
    const int lr = lane & 15, lk = lane >> 4;
    const int m0 = blockIdx.y * 128, n0 = blockIdx.x * 128;
    const int kBeg = blockIdx.z * kChunk;
    const int rsub = lane >> 3;
    const int csub = (lane & 7) * 8;

    f32x4 acc[4][4];
#pragma unroll
    for (int i = 0; i < 4; i++)
#pragma unroll
        for (int j = 0; j < 4; j++) { f32x4 z = {0.f, 0.f, 0.f, 0.f}; acc[i][j] = z; }

    for (int kt = 0; kt < kChunk; kt += 64) {
        const int k0 = kBeg + kt;
        const u16* Ap; int kk, lda;
        if (k0 < kSplit) { Ap = A0; kk = k0; lda = lda0; }
        else             { Ap = A1; kk = k0 - kSplit; lda = lda1; }
        uint4 ra[4], rb[4];
#pragma unroll
        for (int i = 0; i < 4; i++) {
            const int q = wid * 4 + i;
            const int r = q * 8 + rsub;
            ra[i] = *(const uint4*)(Ap + (size_t)(m0 + r) * lda + kk + csub);
            rb[i] = *(const uint4*)(Wt + (size_t)(n0 + r) * ldw + k0 + csub);
        }
        __syncthreads();
#pragma unroll
        for (int i = 0; i < 4; i++) {
            const int q = wid * 4 + i;
            const int r = q * 8 + rsub;
            *(uint4*)&As[r * 72 + csub] = ra[i];
            *(uint4*)&Bs[r * 72 + csub] = rb[i];
        }
        __syncthreads();
#pragma unroll
        for (int s = 0; s < 2; s++) {
            bf16x8 af[4], bfr[4];
#pragma unroll
            for (int i = 0; i < 4; i++)
                af[i] = *(const bf16x8*)&As[(wm * 64 + i * 16 + lr) * 72 + s * 32 + lk * 8];
#pragma unroll
            for (int j = 0; j < 4; j++)
                bfr[j] = *(const bf16x8*)&Bs[(wn * 64 + j * 16 + lr) * 72 + s * 32 + lk * 8];
#pragma unroll
            for (int i = 0; i < 4; i++)
#pragma unroll
                for (int j = 0; j < 4; j++)
                    acc[i][j] = __builtin_amdgcn_mfma_f32_16x16x32_bf16(af[i], bfr[j], acc[i][j], 0, 0, 0);
        }
    }

    const int rowb = m0 + wm * 64, colb = n0 + wn * 64;
#pragma unroll
    for (int i = 0; i < 4; i++) {
#pragma unroll
        for (int j = 0; j < 4; j++) {
            const int col = colb + j * 16 + lr;
#pragma unroll
            for (int r = 0; r < 4; r++) {
                const int row = rowb + i * 16 + lk * 4 + r;
                float v = acc[i][j][r];
                if (EPI == EPI_PARTIAL) {
                    Cf[(size_t)blockIdx.z * ((size_t)M * N) + (size_t)row * N + col] = v;
                } else {
                    if (bias) v += bias[col];
                    if (EPI == EPI_BF16_RELU || EPI == EPI_F32_RELU) v = fmaxf(v, 0.f);
                    else if (EPI == EPI_F32_SP)  v = softplusf(v);
                    else if (EPI == EPI_F32_SIG) v = 1.f / (1.f + __expf(-v));
                    if (EPI == EPI_BF16_RELU || EPI == EPI_BF16_NONE) Cb[(size_t)row * N + col] = f2b(v);
                    else Cf[(size_t)row * N + col] = v;
                }
            }
        }
    }
}

// ---------- workspace layout (bytes) ----------
static constexpr size_t oPHIXWT  = 0;                      // phixWt; T12 parity-1 in phase B
static constexpr size_t oWCATT   = 1048576;                // wcatF frag layout (8 MB)
static constexpr size_t oEMW2T   = 9437184;                // em2F (256 KB)
static constexpr size_t oESW2T   = 9699328;                // es2F
static constexpr size_t oWIHPHIT = 9961472;
static constexpr size_t oWIHZT   = 16252928;               // wihZF (768 KB)
static constexpr size_t oPMW1T   = 17039360;
static constexpr size_t oPMW2T   = 19136512;
static constexpr size_t oPSW1T   = 19398656;
static constexpr size_t oPSW2T   = 21495808;
static constexpr size_t oDMW1T   = 21757952;
static constexpr size_t oDMW2T   = 24117248;
static constexpr size_t oHS      = 25165824;               // [T+1][B][H] bf16
static constexpr size_t oZBF     = 159907840;              // [T][B][Z] bf16
static constexpr size_t oT12     = 176685056;              // T12 parity-0 [256][2048] bf16
static constexpr size_t oBAR     = 177733632;
static constexpr size_t oKLDT    = 177737728;
static constexpr size_t oNLLT    = 177738752;
static constexpr size_t oPHI     = 177739776;              // [65536][1024] bf16
static constexpr size_t oGIP     = 311957504;              // [65536][3072] bf16
static constexpr size_t WS_NEED  = 714610688;

static constexpr size_t NZ = (size_t)256 * 256 * 128;
static constexpr size_t O_Z  = 3;
static constexpr size_t O_MU = 3 + NZ;
static constexpr size_t O_STD = 3 + 2 * NZ;
static constexpr size_t O_XM = 3 + 3 * NZ;

// ---------- persistent seq kernel: 16 groups x 4 blocks, redundant z/GRU ----------
// h is LDS-resident (replicated per block). One T12-slice exchange per step is
// the only inter-block communication. B operands use frag layouts (coalesced).
__global__ __launch_bounds__(256, 1)
void vrnn_seq(const float* __restrict__ eps,
              const float* __restrict__ em_b1, const float* __restrict__ es_b1,
              const float* __restrict__ em_b2, const float* __restrict__ es_b2,
              const float* __restrict__ gbih, const float* __restrict__ gbhh,
              char* ws, float* out) {
    __shared__ __align__(16) u16 hL[16 * 1032];
    __shared__ __align__(16) u16 POOL[16 * 2056];    // PH (phi) then S12 (T12 full row)
    __shared__ float zmL[2048], zsL[2048];
    __shared__ __align__(16) u16 zL[16 * 136];

    const int bx = blockIdx.x, tid = threadIdx.x;
    const int wid = tid >> 6, lane = tid & 63;
    const int lr = lane & 15, lk = lane >> 4;

    const u16* wcatF = (const u16*)(ws + oWCATT);
    const u16* em2F  = (const u16*)(ws + oEMW2T);
    const u16* es2F  = (const u16*)(ws + oESW2T);
    const u16* wihZF = (const u16*)(ws + oWIHZT);
    const u16* PHI   = (const u16*)(ws + oPHI);
    const u16* GIP   = (const u16*)(ws + oGIP);
    u16* HS    = (u16*)(ws + oHS);
    u16* ZBFg  = (u16*)(ws + oZBF);
    u16* T12p0 = (u16*)(ws + oT12);
    u16* T12p1 = (u16*)(ws + oPHIXWT);
    unsigned* bar = (unsigned*)(ws + oBAR);

    float* outZ  = out + O_Z;
    float* outMu = out + O_MU;
    float* outSd = out + O_STD;

    const int g = bx >> 2, n = bx & 3;
    const int r0 = g * 16;
    u16* PH  = POOL;                 // [16][1032] (phi staging; dead after W1)
    u16* S12 = POOL;                 // [16][2056] (full T12 row; live exch->zm/zs)

    const int ldrow = tid >> 4;      // 0..15
    const int ldc64 = (tid & 15) * 64;
    const int ldc32 = (tid & 15) * 32;

    // ---- init: h0 -> LDS ----
    {
        const u16* src = HS + (size_t)r0 * 1024 + (size_t)ldrow * 1024 + ldc64;
#pragma unroll
        for (int p = 0; p < 8; p++)
            *(uint32x4*)&hL[ldrow * 1032 + ldc64 + p * 8] = *(const uint32x4*)(src + p * 8);
    }
    __syncthreads();

#pragma unroll 1
    for (int t = 0; t < 256; t++) {
        u16* T12p = (t & 1) ? T12p1 : T12p0;

        // ---- stage phi slice into PH ----
        {
            const u16* src = PHI + (size_t)t * 262144 + (size_t)(r0 + ldrow) * 1024 + ldc64;
#pragma unroll
            for (int p = 0; p < 8; p++)
                *(uint32x4*)&PH[ldrow * 1032 + ldc64 + p * 8] = *(const uint32x4*)(src + p * 8);
        }
        __syncthreads();

        // ---- W1: own 512-col slab, K=2048 (h from hL, phi from PH, B frag-stream) ----
        f32x4 acc[8];
#pragma unroll
        for (int i = 0; i < 8; i++) { f32x4 z = {0.f,0.f,0.f,0.f}; acc[i] = z; }
#pragma unroll
        for (int i = 0; i < 8; i++) {
            const u16* bs = wcatF + (size_t)(n * 32 + wid * 8 + i) * 32768 + lk * 128 + lr * 8;
            f32x4 a = {0.f,0.f,0.f,0.f};
            bf16x8 bc = *(const bf16x8*)bs;
#pragma unroll 1
            for (int kq = 0; kq < 64; kq++) {
                bf16x8 bn = bc;
                if (kq < 63) bn = *(const bf16x8*)(bs + (size_t)(kq + 1) * 512);
                const u16* asrc = (kq < 32) ? hL : PH;
                bf16x8 af = *(const bf16x8*)&asrc[lr * 1032 + (kq & 31) * 32 + lk * 8];
                a = __builtin_amdgcn_mfma_f32_16x16x32_bf16(af, bc, a, 0, 0, 0);
                bc = bn;
            }
            acc[i] = a;
        }
        __syncthreads();                         // PH dead

        // ---- epilogue: bias+relu -> S12 (own cols) ----
#pragma unroll
        for (int i = 0; i < 8; i++) {
            const int colg = n * 512 + wid * 128 + i * 16 + lr;
            const float bb = (colg < 1024) ? em_b1[colg] : es_b1[colg - 1024];
#pragma unroll
            for (int r = 0; r < 4; r++)
                S12[(lk * 4 + r) * 2056 + colg] = f2b(fmaxf(acc[i][r] + bb, 0.f));
        }
        __syncthreads();

        // ---- sc1 store own slice + flag ----
        {
            u16* dst = T12p + (size_t)(r0 + ldrow) * 2048 + n * 512 + ldc32;
            const u16* s = &S12[ldrow * 2056 + n * 512 + ldc32];
            st_cv16(dst,      *(const uint32x4*)(s));
            st_cv16(dst + 8,  *(const uint32x4*)(s + 8));
            st_cv16(dst + 16, *(const uint32x4*)(s + 16));
            st_cv16(dst + 24, *(const uint32x4*)(s + 24));
        }
        asm volatile("s_waitcnt vmcnt(0)" ::: "memory");
        __syncthreads();
        if (tid == 0) st_cv4(&bar[(g * 4 + n) * 16], (unsigned)(t + 1));

        // ---- poll 3 siblings, load their slices into S12 ----
        if (tid < 3) {
            const int sib = (tid < n) ? tid : tid + 1;
            while (ld_cv4(&bar[(g * 4 + sib) * 16]) < (unsigned)(t + 1))
                __builtin_amdgcn_s_sleep(2);
        }
        __syncthreads();
#pragma unroll 1
        for (int ss = 0; ss < 3; ss++) {
            const int sib = (ss < n) ? ss : ss + 1;
            const u16* src = T12p + (size_t)(r0 + ldrow) * 2048 + sib * 512 + ldc32;
            uint32x4 v0, v1, v2, v3;
            ld_cv16_issue(v0, src);
            ld_cv16_issue(v1, src + 8);
            ld_cv16_issue(v2, src + 16);
            ld_cv16_issue(v3, src + 24);
            wait_vm0();
            u16* d = &S12[ldrow * 2056 + sib * 512 + ldc32];
            *(uint32x4*)(d)      = v0;
            *(uint32x4*)(d + 8)  = v1;
            *(uint32x4*)(d + 16) = v2;
            *(uint32x4*)(d + 24) = v3;
        }
        __syncthreads();

        // ---- zm/zs (redundant): wave = (half, col-quad); frag-stream B ----
        {
            const int halfz = wid >> 1, cq = wid & 1;
            const u16* WF = (halfz ? es2F : em2F) + (size_t)(cq * 4) * 16384 + lk * 128 + lr * 8;
            const u16* Sr = &S12[lr * 2056 + halfz * 1024];
            f32x4 az0 = {0.f,0.f,0.f,0.f}, az1 = az0, az2 = az0, az3 = az0;
#pragma unroll 1
            for (int kq = 0; kq < 32; kq++) {
                bf16x8 af = *(const bf16x8*)(Sr + kq * 32 + lk * 8);
                az0 = __builtin_amdgcn_mfma_f32_16x16x32_bf16(af, *(const bf16x8*)(WF + (size_t)kq * 512), az0, 0, 0, 0);
                az1 = __builtin_amdgcn_mfma_f32_16x16x32_bf16(af, *(const bf16x8*)(WF + 16384 + (size_t)kq * 512), az1, 0, 0, 0);
                az2 = __builtin_amdgcn_mfma_f32_16x16x32_bf16(af, *(const bf16x8*)(WF + 32768 + (size_t)kq * 512), az2, 0, 0, 0);
                az3 = __builtin_amdgcn_mfma_f32_16x16x32_bf16(af, *(const bf16x8*)(WF + 49152 + (size_t)kq * 512), az3, 0, 0, 0);
            }
#pragma unroll
            for (int q = 0; q < 4; q++) {
                const f32x4 az = (q == 0) ? az0 : (q == 1) ? az1 : (q == 2) ? az2 : az3;
                const int c = cq * 64 + q * 16 + lr;
#pragma unroll
                for (int r = 0; r < 4; r++) {
                    const int row = lk * 4 + r;
                    if (!halfz) zmL[row * 128 + c] = fmaxf(az[r] + em_b2[c], 0.f);
                    else        zsL[row * 128 + c] = softplusf(az[r] + es_b2[c]);
                }
            }
        }
        __syncthreads();

        // ---- z = zm + zs*eps -> zL; block 0 writes outputs ----
        {
            const int row = tid >> 4, col = (tid & 15) * 8;
            const size_t o = (size_t)t * 32768 + (size_t)(r0 + row) * 128 + col;
            const float* ep = eps + o;
            float4 e0 = *(const float4*)ep, e1 = *(const float4*)(ep + 4);
            float zmv[8], zsv[8], zv[8];
#pragma unroll
            for (int i = 0; i < 8; i++) {
                zmv[i] = zmL[row * 128 + col + i];
                zsv[i] = zsL[row * 128 + col + i];
                const float ev = (i < 4) ? (&e0.x)[i] : (&e1.x)[i - 4];
                zv[i] = zmv[i] + zsv[i] * ev;
            }
            uint32x4 zp;
#pragma unroll
            for (int j = 0; j < 4; j++)
                zp[j] = (unsigned)f2b(zv[2 * j]) | ((unsigned)f2b(zv[2 * j + 1]) << 16);
            *(uint32x4*)&zL[row * 136 + col] = zp;
            if (n == 0) {
#pragma unroll
                for (int i = 0; i < 8; i++) {
                    outMu[o + i] = zmv[i];
                    outSd[o + i] = zsv[i];
                    outZ[o + i]  = zv[i];
                }
                *(uint32x4*)(ZBFg + o) = zp;     // plain (phase C only)
            }
        }
        __syncthreads();

        // ---- GRU (redundant, full 1024 cols): frag-stream wihZ; h -> hL ----
        {
            bf16x8 zf0 = *(const bf16x8*)&zL[lr * 136 + lk * 8];
            bf16x8 zf1 = *(const bf16x8*)&zL[lr * 136 + 32 + lk * 8];
            bf16x8 zf2 = *(const bf16x8*)&zL[lr * 136 + 64 + lk * 8];
            bf16x8 zf3 = *(const bf16x8*)&zL[lr * 136 + 96 + lk * 8];
            const u16* gipt = GIP + (size_t)t * 786432;
#pragma unroll 1
            for (int i = 0; i < 16; i++) {
                const int ct = wid * 16 + i;
                const int col = ct * 16 + lr;
                const u16* bR = wihZF + (size_t)ct * 2048 + lk * 128 + lr * 8;
                const u16* bU = bR + 131072;
                const u16* bN = bU + 131072;
                f32x4 aR = {0.f,0.f,0.f,0.f}, aU = aR, aN = aR;
                aR = __builtin_amdgcn_mfma_f32_16x16x32_bf16(zf0, *(const bf16x8*)(bR), aR, 0, 0, 0);
                aR = __builtin_amdgcn_mfma_f32_16x16x32_bf16(zf1, *(const bf16x8*)(bR + 512), aR, 0, 0, 0);
                aR = __builtin_amdgcn_mfma_f32_16x16x32_bf16(zf2, *(const bf16x8*)(bR + 1024), aR, 0, 0, 0);
                aR = __builtin_amdgcn_mfma_f32_16x16x32_bf16(zf3, *(const bf16x8*)(bR + 1536), aR, 0, 0, 0);
                aU = __builtin_amdgcn_mfma_f32_16x16x32_bf16(zf0, *(const bf16x8*)(bU), aU, 0, 0, 0);
                aU = __builtin_amdgcn_mfma_f32_16x16x32_bf16(zf1, *(const bf16x8*)(bU + 512), aU, 0, 0, 0);
                aU = __builtin_amdgcn_mfma_f32_16x16x32_bf16(zf2, *(const bf16x8*)(bU + 1024), aU, 0, 0, 0);
                aU = __builtin_amdgcn_mfma_f32_16x16x32_bf16(zf3, *(const bf16x8*)(bU + 1536), aU, 0, 0, 0);
                aN = __builtin_amdgcn_mfma_f32_16x16x32_bf16(zf0, *(const bf16x8*)(bN), aN, 0, 0, 0);
                aN = __builtin_amdgcn_mfma_f32_16x16x32_bf16(zf1, *(const bf16x8*)(bN + 512), aN, 0, 0, 0);
                aN = __builtin_amdgcn_mfma_f32_16x16x32_bf16(zf2, *(const bf16x8*)(bN + 1024), aN, 0, 0, 0);
                aN = __builtin_amdgcn_mfma_f32_16x16x32_bf16(zf3, *(const bf16x8*)(bN + 1536), aN, 0, 0, 0);
                const float bihR = gbih[col],        bhR = gbhh[col];
                const float bihU = gbih[1024 + col], bhU = gbhh[1024 + col];
                const float bihN = gbih[2048 + col], bhN = gbhh[2048 + col];
#pragma unroll
                for (int r = 0; r < 4; r++) {
                    const u16* gp = gipt + (size_t)(r0 + lk * 4 + r) * 3072;
                    const float gr = aR[r] + b2f(gp[col])        + bihR + bhR;
                    const float gu = aU[r] + b2f(gp[1024 + col]) + bihU + bhU;
                    float gn       = aN[r] + b2f(gp[2048 + col]) + bihN;
                    const float rr_ = 1.f / (1.f + __expf(-gr));
                    const float uu  = 1.f / (1.f + __expf(-gu));
                    gn += rr_ * bhN;
                    const float e2 = __expf(-2.f * fabsf(gn));
                    float th = (1.f - e2) / (1.f + e2);
                    th = (gn < 0.f) ? -th : th;
                    hL[(lk * 4 + r) * 1032 + col] = f2b((1.f - uu) * th);
                }
            }
        }
        __syncthreads();

        // ---- block 0: h -> HS (plain; phase C only) ----
        if (n == 0) {
            u16* dst = HS + (size_t)(t + 1) * 262144 + (size_t)(r0 + ldrow) * 1024 + ldc64;
#pragma unroll
            for (int p = 0; p < 8; p++)
                *(uint32x4*)(dst + p * 8) = *(const uint32x4*)&hL[ldrow * 1032 + ldc64 + p * 8];
        }
    }
}

// ---------- loss ----------
__global__ __launch_bounds__(256)
void loss_per_t(const float* __restrict__ x,
                const float* __restrict__ xm,
                const float* __restrict__ zm, const float* __restrict__ zs,
                const float* __restrict__ pm, const float* __restrict__ ps,
                float* __restrict__ kldT, float* __restrict__ nllT) {
    const int t = blockIdx.x, bb = threadIdx.x;
    float kld = 0.f, nll = 0.f;
    const size_t ozb = ((size_t)t * 256 + bb) * 128;
    for (int zz = 0; zz < 128; zz++) {
        const float qs = zs[ozb + zz], qm = zm[ozb + zz];
        const float pmv = pm[ozb + zz], psv = ps[ozb + zz];
        const float d = qm - pmv;
        kld += logf(psv + EPSC) - logf(qs + EPSC)
             + (qs * qs + d * d) / (2.f * psv * psv + EPSC) - 0.5f;
    }
    const size_t oxb = ((size_t)t * 256 + bb) * 512;
    const size_t oxi = ((size_t)bb * 256 + t) * 512;
    for (int dd = 0; dd < 512; dd++) {
        const float xv = x[oxi + dd];
        float m = xm[oxb + dd];
        m = fminf(fmaxf(m, 1e-6f), 1.f - 1e-6f);
        nll -= xv * logf(m) + (1.f - xv) * log1pf(-m);
    }
    __shared__ float sk[256], sn[256];
    sk[bb] = kld; sn[bb] = nll;
    __syncthreads();
    for (int s = 128; s > 0; s >>= 1) {
        if (bb < s) { sk[bb] += sk[bb + s]; sn[bb] += sn[bb + s]; }
        __syncthreads();
    }
    if (bb == 0) { kldT[t] = sk[0] / 256.f; nllT[t] = sn[0] / 256.f; }
}

__global__ __launch_bounds__(256)
void loss_final(const float* __restrict__ kldT, const float* __restrict__ nllT,
                float* __restrict__ out) {
    const int tid = threadIdx.x;
    __shared__ float s[256];
    s[tid] = kldT[tid] + nllT[tid];
    __syncthreads();
    for (int st = 128; st > 0; st >>= 1) {
        if (tid < st) s[tid] += s[tid + st];
        __syncthreads();
    }
    if (tid == 0) { out[0] = s[0]; out[1] = kldT[255]; out[2] = nllT[255]; }
}

extern "C" void kernel_launch(void* const* d_in, const int* in_sizes, int n_in,
                              void* d_out, int out_size, void* d_ws, size_t ws_size,
                              hipStream_t stream) {
    const float* x      = (const float*)d_in[0];
    const float* eps    = (const float*)d_in[1];
    const float* h0     = (const float*)d_in[2];
    const float* phix_w = (const float*)d_in[3];
    const float* phix_b = (const float*)d_in[4];
    const float* pm_w1  = (const float*)d_in[5];
    const float* pm_b1  = (const float*)d_in[6];
    const float* pm_w2  = (const float*)d_in[7];
    const float* pm_b2  = (const float*)d_in[8];
    const float* ps_w1  = (const float*)d_in[9];
    const float* ps_b1  = (const float*)d_in[10];
    const float* ps_w2  = (const float*)d_in[11];
    const float* ps_b2  = (const float*)d_in[12];
    const float* em_w1  = (const float*)d_in[13];
    const float* em_b1  = (const float*)d_in[14];
    const float* em_w2  = (const float*)d_in[15];
    const float* em_b2  = (const float*)d_in[16];
    const float* es_w1  = (const float*)d_in[17];
    const float* es_b1  = (const float*)d_in[18];
    const float* es_w2  = (const float*)d_in[19];
    const float* es_b2  = (const float*)d_in[20];
    const float* dm_w1  = (const float*)d_in[21];
    const float* dm_b1  = (const float*)d_in[22];
    const float* dm_w2  = (const float*)d_in[23];
    const float* dm_b2  = (const float*)d_in[24];
    const float* gwih   = (const float*)d_in[25];
    const float* gbih   = (const float*)d_in[26];
    const float* gbhh   = (const float*)d_in[27];
    float* out = (float*)d_out;

    if (ws_size < WS_NEED) return;
    char* w = (char*)d_ws;
    u16* phixWt  = (u16*)(w + oPHIXWT);
    u16* wcatF   = (u16*)(w + oWCATT);
    u16* em2F    = (u16*)(w + oEMW2T);
    u16* es2F    = (u16*)(w + oESW2T);
    u16* wihPhiT = (u16*)(w + oWIHPHIT);
    u16* wihZF   = (u16*)(w + oWIHZT);
    u16* pmW1T   = (u16*)(w + oPMW1T);
    u16* pmW2T   = (u16*)(w + oPMW2T);
    u16* psW1T   = (u16*)(w + oPSW1T);
    u16* psW2T   = (u16*)(w + oPSW2T);
    u16* dmW1T   = (u16*)(w + oDMW1T);
    u16* dmW2T   = (u16*)(w + oDMW2T);
    u16* HS      = (u16*)(w + oHS);
    u16* ZBF     = (u16*)(w + oZBF);
    u16* PHI     = (u16*)(w + oPHI);
    u16* GIP     = (u16*)(w + oGIP);
    u16* XbfT    = (u16*)(w + oGIP);                 // dead after phi GEMM
    float* PMbuf = (float*)(w + oGIP);               // phase C only (GIP dead)
    float* PSbuf = (float*)(w + oGIP + 33554432);
    unsigned* bar = (unsigned*)(w + oBAR);
    float* kldT  = (float*)(w + oKLDT);
    float* nllT  = (float*)(w + oNLLT);

    // ---- phase A ----
    conv_x4<<<32768, 256, 0, stream>>>(XbfT, x);
    conv_f32_bf16<<<1024, 256, 0, stream>>>(HS, h0, 262144);
    tr_conv<<<2048, 256, 0, stream>>>(phixWt, phix_w, 512, 1024, 1024);
    conv_fragB<<<2048, 256, 0, stream>>>(wcatF, em_w1, es_w1);
    conv_fragB2<<<64, 256, 0, stream>>>(em2F, em_w2);
    conv_fragB2<<<64, 256, 0, stream>>>(es2F, es_w2);
    tr_conv<<<12288, 256, 0, stream>>>(wihPhiT, gwih, 1024, 3072, 3072);
    conv_fragG<<<192, 256, 0, stream>>>(wihZF, gwih);
    tr_conv<<<4096, 256, 0, stream>>>(pmW1T, pm_w1, 1024, 1024, 1024);
    tr_conv<<<512, 256, 0, stream>>>(pmW2T, pm_w2, 1024, 128, 128);
    tr_conv<<<4096, 256, 0, stream>>>(psW1T, ps_w1, 1024, 1024, 1024);
    tr_conv<<<512, 256, 0, stream>>>(psW2T, ps_w2, 1024, 128, 128);
    tr_conv<<<4608, 256, 0, stream>>>(dmW1T, dm_w1, 1152, 1024, 1024);
    tr_conv<<<2048, 256, 0, stream>>>(dmW2T, dm_w2, 1024, 512, 512);

    gemm128<EPI_BF16_RELU><<<dim3(8, 512, 1), 256, 0, stream>>>(
        XbfT, nullptr, 512, 0, 512, phixWt, 512, phix_b, PHI, nullptr, 65536, 1024, 512, 512);
    gemm128<EPI_BF16_NONE><<<dim3(24, 512, 1), 256, 0, stream>>>(
        PHI, nullptr, 1024, 0, 1024, wihPhiT, 1024, nullptr, GIP, nullptr, 65536, 3072, 1024, 1024);

    // ---- phase B: 64 blocks, no grid barrier ----
    init_ctr<<<1, 256, 0, stream>>>(bar);
    vrnn_seq<<<64, 256, 0, stream>>>(eps, em_b1, es_b1, em_b2, es_b2, gbih, gbhh,
                                     (char*)d_ws, out);

    // ---- phase C ----
    gemm128<EPI_BF16_RELU><<<dim3(8, 512, 1), 256, 0, stream>>>(
        HS, nullptr, 1024, 0, 1024, pmW1T, 1024, pm_b1, PHI, nullptr, 65536, 1024, 1024, 1024);
    gemm128<EPI_F32_RELU><<<dim3(1, 512, 1), 256, 0, stream>>>(
        PHI, nullptr, 1024, 0, 1024, pmW2T, 1024, pm_b2, nullptr, PMbuf, 65536, 128, 1024, 1024);
    gemm128<EPI_BF16_RELU><<<dim3(8, 512, 1), 256, 0, stream>>>(
        HS, nullptr, 1024, 0, 1024, psW1T, 1024, ps_b1, PHI, nullptr, 65536, 1024, 1024, 1024);
    gemm128<EPI_F32_SP><<<dim3(1, 512, 1), 256, 0, stream>>>(
        PHI, nullptr, 1024, 0, 1024, psW2T, 1024, ps_b2, nullptr, PSbuf, 65536, 128, 1024, 1024);
    gemm128<EPI_BF16_RELU><<<dim3(8, 512, 1), 256, 0, stream>>>(
        HS, ZBF, 1024, 128, 1024, dmW1T, 1152, dm_b1, PHI, nullptr, 65536, 1024, 1152, 1152);
    gemm128<EPI_F32_SIG><<<dim3(4, 512, 1), 256, 0, stream>>>(
        PHI, nullptr, 1024, 0, 1024, dmW2T, 1024, dm_b2, nullptr, out + O_XM, 65536, 512, 1024, 1024);

    loss_per_t<<<256, 256, 0, stream>>>(x, out + O_XM, out + O_MU, out + O_STD,
                                        PMbuf, PSbuf, kldT, nllT);
    loss_final<<<1, 256, 0, stream>>>(kldT, nllT, out);
}

// Round 15
// 21339.290 us; speedup vs baseline: 2.4877x; 2.4877x over previous
//
#include <hip/hip_runtime.h>

typedef unsigned short u16;
typedef __bf16 bf16x8 __attribute__((ext_vector_type(8)));
typedef float f32x4 __attribute__((ext_vector_type(4)));
typedef unsigned uint32x4 __attribute__((ext_vector_type(4)));

#define EPSC 1e-6f

// ---------- helpers ----------
__device__ __forceinline__ float b2f(u16 x) { return __uint_as_float(((unsigned)x) << 16); }
__device__ __forceinline__ u16 f2b(float f) {
    unsigned u = __float_as_uint(f);
    unsigned r = (u + 0x7fffu + ((u >> 16) & 1u)) >> 16;
    return (u16)r;
}
__device__ __forceinline__ float softplusf(float x) {
    return fmaxf(x, 0.f) + log1pf(__expf(-fabsf(x)));
}

// ---------- conversion / transpose kernels ----------
__global__ void conv_x4(u16* __restrict__ dst, const float* __restrict__ x) {
    size_t i4 = (size_t)blockIdx.x * 256 + threadIdx.x;
    size_t o = i4 * 4;
    int d = (int)(o & 511);
    int b = (int)((o >> 9) & 255);
    int t = (int)(o >> 17);
    float4 v = *(const float4*)(x + ((size_t)b * 256 + t) * 512 + d);
    unsigned p0 = (unsigned)f2b(v.x) | ((unsigned)f2b(v.y) << 16);
    unsigned p1 = (unsigned)f2b(v.z) | ((unsigned)f2b(v.w) << 16);
    *(uint2*)(dst + o) = make_uint2(p0, p1);
}

__global__ void conv_f32_bf16(u16* __restrict__ dst, const float* __restrict__ src, int n) {
    int i = blockIdx.x * 256 + threadIdx.x;
    if (i < n) dst[i] = f2b(src[i]);
}

__global__ void tr_conv(u16* __restrict__ dst, const float* __restrict__ src,
                        int R, int C, int ld) {
    int idx = blockIdx.x * 256 + threadIdx.x;
    if (idx >= R * C) return;
    int c = idx / R, r = idx % R;
    dst[idx] = f2b(src[(size_t)r * ld + c]);
}

// MFMA B-frag layouts (verified round 14): contiguous 1KB per wave B-frag read.
__global__ void conv_fragB(u16* __restrict__ dst, const float* __restrict__ em1,
                           const float* __restrict__ es1) {
    int idx = blockIdx.x * 256 + threadIdx.x;       // 524288 threads
    int col = idx >> 8, kb = idx & 255;
    int k = kb * 8, ct = col >> 4, lr = col & 15, kq = kb >> 2, lk = kb & 3;
    size_t off = ((size_t)ct * 64 + kq) * 512 + lk * 128 + lr * 8;
    const float* src = (col < 1024) ? em1 : es1;
    const int c = (col < 1024) ? col : col - 1024;
#pragma unroll
    for (int j = 0; j < 8; j++)
        dst[off + j] = f2b(src[(size_t)(k + j) * 1024 + c]);
}

__global__ void conv_fragB2(u16* __restrict__ dst, const float* __restrict__ src) {
    int idx = blockIdx.x * 256 + threadIdx.x;       // 16384 threads
    int col = idx >> 7, kb = idx & 127;
    int k = kb * 8, ct = col >> 4, lr = col & 15, kq = kb >> 2, lk = kb & 3;
    size_t off = ((size_t)ct * 32 + kq) * 512 + lk * 128 + lr * 8;
#pragma unroll
    for (int j = 0; j < 8; j++)
        dst[off + j] = f2b(src[(size_t)(k + j) * 128 + col]);
}

__global__ void conv_fragG(u16* __restrict__ dst, const float* __restrict__ gwih) {
    int idx = blockIdx.x * 256 + threadIdx.x;       // 49152 threads
    int gate = idx >> 14, rem = idx & 16383;
    int col = rem >> 4, kb = rem & 15;
    int k = kb * 8, ct = col >> 4, lr = col & 15, kq = kb >> 2, lk = kb & 3;
    size_t off = (size_t)gate * 131072 + ((size_t)ct * 4 + kq) * 512 + lk * 128 + lr * 8;
#pragma unroll
    for (int j = 0; j < 8; j++)
        dst[off + j] = f2b(gwih[(size_t)(1024 + k + j) * 3072 + gate * 1024 + col]);
}

// ---------- generic 128x128 bf16 MFMA GEMM (phase A/C) ----------
enum { EPI_PARTIAL = 0, EPI_BF16_RELU = 1, EPI_BF16_NONE = 2,
       EPI_F32_RELU = 3, EPI_F32_SP = 4, EPI_F32_SIG = 5, EPI_TGIP = 6 };

template <int EPI>
__global__ __launch_bounds__(256)
void gemm128(const u16* __restrict__ A0, const u16* __restrict__ A1,
             int lda0, int lda1, int kSplit,
             const u16* __restrict__ Wt, int ldw,
             const float* __restrict__ bias,
             u16* __restrict__ Cb, float* __restrict__ Cf,
             int M, int N, int K, int kChunk) {
    __shared__ __align__(16) u16 As[128 * 72];
    __shared__ __align__(16) u16 Bs[128 * 72];
    const int tid = threadIdx.x;
    const int wid = tid >> 6, lane = tid & 63;
    const int wm = wid >> 1, wn = wid & 1;
    const int lr = lane & 15, lk = lane >> 4;
    const int m0 = blockIdx.y * 128, n0 = blockIdx.x * 128;
    const int kBeg = blockIdx.z * kChunk;
    const int rsub = lane >> 3;
    const int csub = (lane & 7) * 8;

    f32x4 acc[4][4];
#pragma unroll
    for (int i = 0; i < 4; i++)
#pragma unroll
        for (int j = 0; j < 4; j++) { f32x4 z = {0.f, 0.f, 0.f, 0.f}; acc[i][j] = z; }

    for (int kt = 0; kt < kChunk; kt += 64) {
        const int k0 = kBeg + kt;
        const u16* Ap; int kk, lda;
        if (k0 < kSplit) { Ap = A0; kk = k0; lda = lda0; }
        else             { Ap = A1; kk = k0 - kSplit; lda = lda1; }
        uint4 ra[4], rb[4];
#pragma unroll
        for (int i = 0; i < 4; i++) {
            const int q = wid * 4 + i;
            const int r = q * 8 + rsub;
            ra[i] = *(const uint4*)(Ap + (size_t)(m0 + r) * lda + kk + csub);
            rb[i] = *(const uint4*)(Wt + (size_t)(n0 + r) * ldw + k0 + csub);
        }
        __syncthreads();
#pragma unroll
        for (int i = 0; i < 4; i++) {
            const int q = wid * 4 + i;
            const int r = q * 8 + rsub;
            *(uint4*)&As[r * 72 + csub] = ra[i];
            *(uint4*)&Bs[r * 72 + csub] = rb[i];
        }
        __syncthreads();
#pragma unroll
        for (int s = 0; s < 2; s++) {
            bf16x8 af[4], bfr[4];
#pragma unroll
            for (int i = 0; i < 4; i++)
                af[i] = *(const bf16x8*)&As[(wm * 64 + i * 16 + lr) * 72 + s * 32 + lk * 8];
#pragma unroll
            for (int j = 0; j < 4; j++)
                bfr[j] = *(const bf16x8*)&Bs[(wn * 64 + j * 16 + lr) * 72 + s * 32 + lk * 8];
#pragma unroll
            for (int i = 0; i < 4; i++)
#pragma unroll
                for (int j = 0; j < 4; j++)
                    acc[i][j] = __builtin_amdgcn_mfma_f32_16x16x32_bf16(af[i], bfr[j], acc[i][j], 0, 0, 0);
        }
    }

    const int rowb = m0 + wm * 64, colb = n0 + wn * 64;
#pragma unroll
    for (int i = 0; i < 4; i++) {
#pragma unroll
        for (int j = 0; j < 4; j++) {
            const int col = colb + j * 16 + lr;
            if (EPI == EPI_TGIP) {
                // transposed GIP: dst[((t*3+gate)*1024+cc)*256 + b], b contiguous per thread
                const int row0 = rowb + i * 16 + lk * 4;
                const int tt = row0 >> 8, b0 = row0 & 255;
                const int gate = col >> 10, cc = col & 1023;
                unsigned lo = (unsigned)f2b(acc[i][j][0]) | ((unsigned)f2b(acc[i][j][1]) << 16);
                unsigned hi = (unsigned)f2b(acc[i][j][2]) | ((unsigned)f2b(acc[i][j][3]) << 16);
                *(uint2*)(Cb + (((size_t)tt * 3 + gate) * 1024 + cc) * 256 + b0) = make_uint2(lo, hi);
            } else {
#pragma unroll
                for (int r = 0; r < 4; r++) {
                    const int row = rowb + i * 16 + lk * 4 + r;
                    float v = acc[i][j][r];
                    if (EPI == EPI_PARTIAL) {
                        Cf[(size_t)blockIdx.z * ((size_t)M * N) + (size_t)row * N + col] = v;
                    } else {
                        if (bias) v += bias[col];
                        if (EPI == EPI_BF16_RELU || EPI == EPI_F32_RELU) v = fmaxf(v, 0.f);
                        else if (EPI == EPI_F32_SP)  v = softplusf(v);
                        else if (EPI == EPI_F32_SIG) v = 1.f / (1.f + __expf(-v));
                        if (EPI == EPI_BF16_RELU || EPI == EPI_BF16_NONE) Cb[(size_t)row * N + col] = f2b(v);
                        else Cf[(size_t)row * N + col] = v;
                    }
                }
            }
        }
    }
}

// ---------- workspace layout (bytes) ----------
static constexpr size_t oPHIXWT  = 0;                      // phixWt; T12 parity-1 in phase B
static constexpr size_t oWCATT   = 1048576;                // wcatF frag (8 MB)
static constexpr size_t oEMW2T   = 9437184;                // em2F
static constexpr size_t oESW2T   = 9699328;                // es2F
static constexpr size_t oWIHPHIT = 9961472;
static constexpr size_t oWIHZT   = 16252928;               // wihZF
static constexpr size_t oPMW1T   = 17039360;
static constexpr size_t oPMW2T   = 19136512;
static constexpr size_t oPSW1T   = 19398656;
static constexpr size_t oPSW2T   = 21495808;
static constexpr size_t oDMW1T   = 21757952;
static constexpr size_t oDMW2T   = 24117248;
static constexpr size_t oHS      = 25165824;               // [T+1][B][H] bf16
static constexpr size_t oZBF     = 159907840;              // [T][B][Z] bf16
static constexpr size_t oT12     = 176685056;              // T12 parity-0 [256][2048] bf16
static constexpr size_t oBAR     = 177733632;
static constexpr size_t oKLDT    = 177737728;
static constexpr size_t oNLLT    = 177738752;
static constexpr size_t oPHI     = 177739776;              // [65536][1024] bf16
static constexpr size_t oGIP     = 311957504;              // GIPT [256][3][1024][256] bf16
static constexpr size_t WS_NEED  = 714610688;

static constexpr size_t NZ = (size_t)256 * 256 * 128;
static constexpr size_t O_Z  = 3;
static constexpr size_t O_MU = 3 + NZ;
static constexpr size_t O_STD = 3 + 2 * NZ;
static constexpr size_t O_XM = 3 + 3 * NZ;

// ---------- per-step fused kernel (launch-per-step; kernel boundary = sync) ----------
// 256 blocks = 16 groups x 16. Block (g,n): stage T12(t) -> redundant zm/zs/z ->
// redundant GRU -> h(t+1) in LDS -> W1 for its 128-col slab -> T12(t+1).
// Block n==0 writes mu/sd/z/ZBF/HS. Plain loads/stores only.
__global__ __launch_bounds__(256, 1)
void vrnn_step(int t, int prolog,
               const float* __restrict__ eps,
               const float* __restrict__ em_b1, const float* __restrict__ es_b1,
               const float* __restrict__ em_b2, const float* __restrict__ es_b2,
               const float* __restrict__ gbih, const float* __restrict__ gbhh,
               char* ws, float* out) {
    __shared__ __align__(16) u16 POOL[16 * 2056];   // S12; later {hL, PH}
    __shared__ float zmL[2048], zsL[2048];
    __shared__ __align__(16) u16 zTH[16 * 136];     // z storage, then W1 epilogue

    const int bx = blockIdx.x, tid = threadIdx.x;
    const int wid = tid >> 6, lane = tid & 63;
    const int lr = lane & 15, lk = lane >> 4;
    const int g = bx >> 4, n = bx & 15;
    const int r0 = g * 16;

    const u16* wcatF = (const u16*)(ws + oWCATT);
    const u16* em2F  = (const u16*)(ws + oEMW2T);
    const u16* es2F  = (const u16*)(ws + oESW2T);
    const u16* wihZF = (const u16*)(ws + oWIHZT);
    const u16* PHI   = (const u16*)(ws + oPHI);
    const u16* GIPT  = (const u16*)(ws + oGIP);
    u16* HS    = (u16*)(ws + oHS);
    u16* ZBFg  = (u16*)(ws + oZBF);
    u16* T12p0 = (u16*)(ws + oT12);
    u16* T12p1 = (u16*)(ws + oPHIXWT);

    float* outZ  = out + O_Z;
    float* outMu = out + O_MU;
    float* outSd = out + O_STD;

    u16* S12 = POOL;                 // [16][2056]
    u16* hL  = POOL;                 // [16][1032]
    u16* PH  = POOL + 16 * 1032;     // [16][1032]

    const int srow = tid >> 4, sc8 = (tid & 15) * 8;

    if (!prolog) {
        // ---- stage T12(t) -> S12 ----
        {
            const u16* src = ((t & 1) ? T12p1 : T12p0) + (size_t)(r0 + srow) * 2048 + sc8;
#pragma unroll
            for (int p = 0; p < 16; p++)
                *(uint32x4*)&S12[srow * 2056 + sc8 + p * 128] = *(const uint32x4*)(src + p * 128);
        }
        __syncthreads();

        // ---- zm/zs (redundant; frag-stream W2) ----
        {
            const int halfz = wid >> 1, cq = wid & 1;
            const u16* WF = (halfz ? es2F : em2F) + (size_t)(cq * 4) * 16384 + lk * 128 + lr * 8;
            const u16* Sr = &S12[lr * 2056 + halfz * 1024];
            f32x4 az0 = {0.f,0.f,0.f,0.f}, az1 = az0, az2 = az0, az3 = az0;
#pragma unroll 1
            for (int kq = 0; kq < 32; kq++) {
                bf16x8 af = *(const bf16x8*)(Sr + kq * 32 + lk * 8);
                az0 = __builtin_amdgcn_mfma_f32_16x16x32_bf16(af, *(const bf16x8*)(WF + (size_t)kq * 512), az0, 0, 0, 0);
                az1 = __builtin_amdgcn_mfma_f32_16x16x32_bf16(af, *(const bf16x8*)(WF + 16384 + (size_t)kq * 512), az1, 0, 0, 0);
                az2 = __builtin_amdgcn_mfma_f32_16x16x32_bf16(af, *(const bf16x8*)(WF + 32768 + (size_t)kq * 512), az2, 0, 0, 0);
                az3 = __builtin_amdgcn_mfma_f32_16x16x32_bf16(af, *(const bf16x8*)(WF + 49152 + (size_t)kq * 512), az3, 0, 0, 0);
            }
#pragma unroll
            for (int q = 0; q < 4; q++) {
                const f32x4 az = (q == 0) ? az0 : (q == 1) ? az1 : (q == 2) ? az2 : az3;
                const int c = cq * 64 + q * 16 + lr;
#pragma unroll
                for (int r = 0; r < 4; r++) {
                    const int row = lk * 4 + r;
                    if (!halfz) zmL[row * 128 + c] = fmaxf(az[r] + em_b2[c], 0.f);
                    else        zsL[row * 128 + c] = softplusf(az[r] + es_b2[c]);
                }
            }
        }
        __syncthreads();

        // ---- z = zm + zs*eps -> zTH; n==0 writes outputs ----
        {
            const int row = tid >> 4, col = (tid & 15) * 8;
            const size_t o = (size_t)t * 32768 + (size_t)(r0 + row) * 128 + col;
            const float* ep = eps + o;
            float4 e0 = *(const float4*)ep, e1 = *(const float4*)(ep + 4);
            float zmv[8], zsv[8], zv[8];
#pragma unroll
            for (int i = 0; i < 8; i++) {
                zmv[i] = zmL[row * 128 + col + i];
                zsv[i] = zsL[row * 128 + col + i];
                const float ev = (i < 4) ? (&e0.x)[i] : (&e1.x)[i - 4];
                zv[i] = zmv[i] + zsv[i] * ev;
            }
            uint32x4 zp;
#pragma unroll
            for (int j = 0; j < 4; j++)
                zp[j] = (unsigned)f2b(zv[2 * j]) | ((unsigned)f2b(zv[2 * j + 1]) << 16);
            *(uint32x4*)&zTH[row * 136 + col] = zp;
            if (n == 0) {
#pragma unroll
                for (int i = 0; i < 8; i++) {
                    outMu[o + i] = zmv[i];
                    outSd[o + i] = zsv[i];
                    outZ[o + i]  = zv[i];
                }
                *(uint32x4*)(ZBFg + o) = zp;
            }
        }
        __syncthreads();

        // ---- GRU (redundant, full 1024 cols): frag-stream wihZ; GIPT coalesced ----
        {
            bf16x8 zf0 = *(const bf16x8*)&zTH[lr * 136 + lk * 8];
            bf16x8 zf1 = *(const bf16x8*)&zTH[lr * 136 + 32 + lk * 8];
            bf16x8 zf2 = *(const bf16x8*)&zTH[lr * 136 + 64 + lk * 8];
            bf16x8 zf3 = *(const bf16x8*)&zTH[lr * 136 + 96 + lk * 8];
            const u16* gT = GIPT + (size_t)t * 786432;
#pragma unroll 1
            for (int i = 0; i < 16; i++) {
                const int ct = wid * 16 + i;
                const int col = ct * 16 + lr;
                const u16* bR = wihZF + (size_t)ct * 2048 + lk * 128 + lr * 8;
                const u16* bU = bR + 131072;
                const u16* bN = bU + 131072;
                f32x4 aR = {0.f,0.f,0.f,0.f}, aU = aR, aN = aR;
                aR = __builtin_amdgcn_mfma_f32_16x16x32_bf16(zf0, *(const bf16x8*)(bR), aR, 0, 0, 0);
                aR = __builtin_amdgcn_mfma_f32_16x16x32_bf16(zf1, *(const bf16x8*)(bR + 512), aR, 0, 0, 0);
                aR = __builtin_amdgcn_mfma_f32_16x16x32_bf16(zf2, *(const bf16x8*)(bR + 1024), aR, 0, 0, 0);
                aR = __builtin_amdgcn_mfma_f32_16x16x32_bf16(zf3, *(const bf16x8*)(bR + 1536), aR, 0, 0, 0);
                aU = __builtin_amdgcn_mfma_f32_16x16x32_bf16(zf0, *(const bf16x8*)(bU), aU, 0, 0, 0);
                aU = __builtin_amdgcn_mfma_f32_16x16x32_bf16(zf1, *(const bf16x8*)(bU + 512), aU, 0, 0, 0);
                aU = __builtin_amdgcn_mfma_f32_16x16x32_bf16(zf2, *(const bf16x8*)(bU + 1024), aU, 0, 0, 0);
                aU = __builtin_amdgcn_mfma_f32_16x16x32_bf16(zf3, *(const bf16x8*)(bU + 1536), aU, 0, 0, 0);
                aN = __builtin_amdgcn_mfma_f32_16x16x32_bf16(zf0, *(const bf16x8*)(bN), aN, 0, 0, 0);
                aN = __builtin_amdgcn_mfma_f32_16x16x32_bf16(zf1, *(const bf16x8*)(bN + 512), aN, 0, 0, 0);
                aN = __builtin_amdgcn_mfma_f32_16x16x32_bf16(zf2, *(const bf16x8*)(bN + 1024), aN, 0, 0, 0);
                aN = __builtin_amdgcn_mfma_f32_16x16x32_bf16(zf3, *(const bf16x8*)(bN + 1536), aN, 0, 0, 0);
                // coalesced transposed-GIP gate values: 8B per gate
                const size_t gb = (size_t)col * 256 + r0 + lk * 4;
                uint2 gR2 = *(const uint2*)(gT + gb);
                uint2 gU2 = *(const uint2*)(gT + 262144 + gb);
                uint2 gN2 = *(const uint2*)(gT + 524288 + gb);
                const u16 gRv[4] = {(u16)(gR2.x & 0xffff), (u16)(gR2.x >> 16),
                                    (u16)(gR2.y & 0xffff), (u16)(gR2.y >> 16)};
                const u16 gUv[4] = {(u16)(gU2.x & 0xffff), (u16)(gU2.x >> 16),
                                    (u16)(gU2.y & 0xffff), (u16)(gU2.y >> 16)};
                const u16 gNv[4] = {(u16)(gN2.x & 0xffff), (u16)(gN2.x >> 16),
                                    (u16)(gN2.y & 0xffff), (u16)(gN2.y >> 16)};
                const float bihR = gbih[col],        bhR = gbhh[col];
                const float bihU = gbih[1024 + col], bhU = gbhh[1024 + col];
                const float bihN = gbih[2048 + col], bhN = gbhh[2048 + col];
#pragma unroll
                for (int r = 0; r < 4; r++) {
                    const float gr = aR[r] + b2f(gRv[r]) + bihR + bhR;
                    const float gu = aU[r] + b2f(gUv[r]) + bihU + bhU;
                    float gn       = aN[r] + b2f(gNv[r]) + bihN;
                    const float rr_ = 1.f / (1.f + __expf(-gr));
                    const float uu  = 1.f / (1.f + __expf(-gu));
                    gn += rr_ * bhN;
                    const float e2 = __expf(-2.f * fabsf(gn));
                    float th = (1.f - e2) / (1.f + e2);
                    th = (gn < 0.f) ? -th : th;
                    hL[(lk * 4 + r) * 1032 + col] = f2b((1.f - uu) * th);
                }
            }
        }
        __syncthreads();

        // ---- n==0: write HS(t+1) for phase C ----
        if (n == 0) {
            u16* dstH = HS + (size_t)(t + 1) * 262144 + (size_t)(r0 + srow) * 1024 + sc8;
#pragma unroll
            for (int p = 0; p < 8; p++)
                *(uint32x4*)(dstH + p * 128) = *(const uint32x4*)&hL[srow * 1032 + sc8 + p * 128];
        }
    } else {
        // prologue: hL <- h0 (HS slot 0)
        const u16* src = HS + (size_t)(r0 + srow) * 1024 + sc8;
#pragma unroll
        for (int p = 0; p < 8; p++)
            *(uint32x4*)&hL[srow * 1032 + sc8 + p * 128] = *(const uint32x4*)(src + p * 128);
        __syncthreads();
    }

    // ---- W1 for step t+1: T12(t+1) = [h(t+1) | phi(t+1)] @ wcat, own 128 cols ----
    if (t < 255) {
        // stage phi(t+1)
        {
            const u16* psrc = PHI + (size_t)(t + 1) * 262144 + (size_t)(r0 + srow) * 1024 + sc8;
#pragma unroll
            for (int p = 0; p < 8; p++)
                *(uint32x4*)&PH[srow * 1032 + sc8 + p * 128] = *(const uint32x4*)(psrc + p * 128);
        }
        __syncthreads();

        f32x4 a0 = {0.f,0.f,0.f,0.f}, a1 = {0.f,0.f,0.f,0.f};
        const int ct0 = n * 8 + wid * 2;
        const u16* b0s = wcatF + (size_t)ct0 * 32768 + lk * 128 + lr * 8;
        const u16* b1s = b0s + 32768;
#pragma unroll 1
        for (int kq = 0; kq < 32; kq++) {                // h half
            bf16x8 af = *(const bf16x8*)&hL[lr * 1032 + kq * 32 + lk * 8];
            a0 = __builtin_amdgcn_mfma_f32_16x16x32_bf16(af, *(const bf16x8*)(b0s + (size_t)kq * 512), a0, 0, 0, 0);
            a1 = __builtin_amdgcn_mfma_f32_16x16x32_bf16(af, *(const bf16x8*)(b1s + (size_t)kq * 512), a1, 0, 0, 0);
        }
#pragma unroll 1
        for (int kq = 32; kq < 64; kq++) {               // phi half
            bf16x8 af = *(const bf16x8*)&PH[lr * 1032 + (kq - 32) * 32 + lk * 8];
            a0 = __builtin_amdgcn_mfma_f32_16x16x32_bf16(af, *(const bf16x8*)(b0s + (size_t)kq * 512), a0, 0, 0, 0);
            a1 = __builtin_amdgcn_mfma_f32_16x16x32_bf16(af, *(const bf16x8*)(b1s + (size_t)kq * 512), a1, 0, 0, 0);
        }
        __syncthreads();
        // epilogue: bias+relu -> zTH repack -> coalesced global store
#pragma unroll
        for (int i = 0; i < 2; i++) {
            const f32x4 a = i ? a1 : a0;
            const int lct = wid * 2 + i;
            const int colg = n * 128 + lct * 16 + lr;
            const float bb = (colg < 1024) ? em_b1[colg] : es_b1[colg - 1024];
#pragma unroll
            for (int r = 0; r < 4; r++)
                zTH[(lk * 4 + r) * 136 + lct * 16 + lr] = f2b(fmaxf(a[r] + bb, 0.f));
        }
        __syncthreads();
        {
            u16* dst = ((t & 1) ? T12p0 : T12p1) + (size_t)(r0 + srow) * 2048 + n * 128 + sc8;
            *(uint32x4*)dst = *(const uint32x4*)&zTH[srow * 136 + sc8];
        }
    }
}

// ---------- loss ----------
__global__ __launch_bounds__(256)
void loss_per_t(const float* __restrict__ x,
                const float* __restrict__ xm,
                const float* __restrict__ zm, const float* __restrict__ zs,
                const float* __restrict__ pm, const float* __restrict__ ps,
                float* __restrict__ kldT, float* __restrict__ nllT) {
    const int t = blockIdx.x, bb = threadIdx.x;
    float kld = 0.f, nll = 0.f;
    const size_t ozb = ((size_t)t * 256 + bb) * 128;
    for (int zz = 0; zz < 128; zz++) {
        const float qs = zs[ozb + zz], qm = zm[ozb + zz];
        const float pmv = pm[ozb + zz], psv = ps[ozb + zz];
        const float d = qm - pmv;
        kld += logf(psv + EPSC) - logf(qs + EPSC)
             + (qs * qs + d * d) / (2.f * psv * psv + EPSC) - 0.5f;
    }
    const size_t oxb = ((size_t)t * 256 + bb) * 512;
    const size_t oxi = ((size_t)bb * 256 + t) * 512;
    for (int dd = 0; dd < 512; dd++) {
        const float xv = x[oxi + dd];
        float m = xm[oxb + dd];
        m = fminf(fmaxf(m, 1e-6f), 1.f - 1e-6f);
        nll -= xv * logf(m) + (1.f - xv) * log1pf(-m);
    }
    __shared__ float sk[256], sn[256];
    sk[bb] = kld; sn[bb] = nll;
    __syncthreads();
    for (int s = 128; s > 0; s >>= 1) {
        if (bb < s) { sk[bb] += sk[bb + s]; sn[bb] += sn[bb + s]; }
        __syncthreads();
    }
    if (bb == 0) { kldT[t] = sk[0] / 256.f; nllT[t] = sn[0] / 256.f; }
}

__global__ __launch_bounds__(256)
void loss_final(const float* __restrict__ kldT, const float* __restrict__ nllT,
                float* __restrict__ out) {
    const int tid = threadIdx.x;
    __shared__ float s[256];
    s[tid] = kldT[tid] + nllT[tid];
    __syncthreads();
    for (int st = 128; st > 0; st >>= 1) {
        if (tid < st) s[tid] += s[tid + st];
        __syncthreads();
    }
    if (tid == 0) { out[0] = s[0]; out[1] = kldT[255]; out[2] = nllT[255]; }
}

extern "C" void kernel_launch(void* const* d_in, const int* in_sizes, int n_in,
                              void* d_out, int out_size, void* d_ws, size_t ws_size,
                              hipStream_t stream) {
    const float* x      = (const float*)d_in[0];
    const float* eps    = (const float*)d_in[1];
    const float* h0     = (const float*)d_in[2];
    const float* phix_w = (const float*)d_in[3];
    const float* phix_b = (const float*)d_in[4];
    const float* pm_w1  = (const float*)d_in[5];
    const float* pm_b1  = (const float*)d_in[6];
    const float* pm_w2  = (const float*)d_in[7];
    const float* pm_b2  = (const float*)d_in[8];
    const float* ps_w1  = (const float*)d_in[9];
    const float* ps_b1  = (const float*)d_in[10];
    const float* ps_w2  = (const float*)d_in[11];
    const float* ps_b2  = (const float*)d_in[12];
    const float* em_w1  = (const float*)d_in[13];
    const float* em_b1  = (const float*)d_in[14];
    const float* em_w2  = (const float*)d_in[15];
    const float* em_b2  = (const float*)d_in[16];
    const float* es_w1  = (const float*)d_in[17];
    const float* es_b1  = (const float*)d_in[18];
    const float* es_w2  = (const float*)d_in[19];
    const float* es_b2  = (const float*)d_in[20];
    const float* dm_w1  = (const float*)d_in[21];
    const float* dm_b1  = (const float*)d_in[22];
    const float* dm_w2  = (const float*)d_in[23];
    const float* dm_b2  = (const float*)d_in[24];
    const float* gwih   = (const float*)d_in[25];
    const float* gbih   = (const float*)d_in[26];
    const float* gbhh   = (const float*)d_in[27];
    float* out = (float*)d_out;

    if (ws_size < WS_NEED) return;
    char* w = (char*)d_ws;
    u16* phixWt  = (u16*)(w + oPHIXWT);
    u16* wcatF   = (u16*)(w + oWCATT);
    u16* em2F    = (u16*)(w + oEMW2T);
    u16* es2F    = (u16*)(w + oESW2T);
    u16* wihPhiT = (u16*)(w + oWIHPHIT);
    u16* wihZF   = (u16*)(w + oWIHZT);
    u16* pmW1T   = (u16*)(w + oPMW1T);
    u16* pmW2T   = (u16*)(w + oPMW2T);
    u16* psW1T   = (u16*)(w + oPSW1T);
    u16* psW2T   = (u16*)(w + oPSW2T);
    u16* dmW1T   = (u16*)(w + oDMW1T);
    u16* dmW2T   = (u16*)(w + oDMW2T);
    u16* HS      = (u16*)(w + oHS);
    u16* ZBF     = (u16*)(w + oZBF);
    u16* PHI     = (u16*)(w + oPHI);
    u16* GIPT    = (u16*)(w + oGIP);
    u16* XbfT    = (u16*)(w + oGIP);                 // dead after phi GEMM
    float* PMbuf = (float*)(w + oGIP);               // phase C only (GIPT dead)
    float* PSbuf = (float*)(w + oGIP + 33554432);
    float* kldT  = (float*)(w + oKLDT);
    float* nllT  = (float*)(w + oNLLT);

    // ---- phase A ----
    conv_x4<<<32768, 256, 0, stream>>>(XbfT, x);
    conv_f32_bf16<<<1024, 256, 0, stream>>>(HS, h0, 262144);
    tr_conv<<<2048, 256, 0, stream>>>(phixWt, phix_w, 512, 1024, 1024);
    conv_fragB<<<2048, 256, 0, stream>>>(wcatF, em_w1, es_w1);
    conv_fragB2<<<64, 256, 0, stream>>>(em2F, em_w2);
    conv_fragB2<<<64, 256, 0, stream>>>(es2F, es_w2);
    tr_conv<<<12288, 256, 0, stream>>>(wihPhiT, gwih, 1024, 3072, 3072);
    conv_fragG<<<192, 256, 0, stream>>>(wihZF, gwih);
    tr_conv<<<4096, 256, 0, stream>>>(pmW1T, pm_w1, 1024, 1024, 1024);
    tr_conv<<<512, 256, 0, stream>>>(pmW2T, pm_w2, 1024, 128, 128);
    tr_conv<<<4096, 256, 0, stream>>>(psW1T, ps_w1, 1024, 1024, 1024);
    tr_conv<<<512, 256, 0, stream>>>(psW2T, ps_w2, 1024, 128, 128);
    tr_conv<<<4608, 256, 0, stream>>>(dmW1T, dm_w1, 1152, 1024, 1024);
    tr_conv<<<2048, 256, 0, stream>>>(dmW2T, dm_w2, 1024, 512, 512);

    gemm128<EPI_BF16_RELU><<<dim3(8, 512, 1), 256, 0, stream>>>(
        XbfT, nullptr, 512, 0, 512, phixWt, 512, phix_b, PHI, nullptr, 65536, 1024, 512, 512);
    // GIPT = transpose(phi @ gru_wih[:H])  (overwrites XbfT region)
    gemm128<EPI_TGIP><<<dim3(24, 512, 1), 256, 0, stream>>>(
        PHI, nullptr, 1024, 0, 1024, wihPhiT, 1024, nullptr, GIPT, nullptr, 65536, 3072, 1024, 1024);

    // ---- phase B: 257 step launches (kernel boundary = device-wide sync) ----
    vrnn_step<<<256, 256, 0, stream>>>(-1, 1, eps, em_b1, es_b1, em_b2, es_b2,
                                       gbih, gbhh, (char*)d_ws, out);
    for (int t = 0; t < 256; t++)
        vrnn_step<<<256, 256, 0, stream>>>(t, 0, eps, em_b1, es_b1, em_b2, es_b2,
                                           gbih, gbhh, (char*)d_ws, out);

    // ---- phase C ----
    gemm128<EPI_BF16_RELU><<<dim3(8, 512, 1), 256, 0, stream>>>(
        HS, nullptr, 1024, 0, 1024, pmW1T, 1024, pm_b1, PHI, nullptr, 65536, 1024, 1024, 1024);
    gemm128<EPI_F32_RELU><<<dim3(1, 512, 1), 256, 0, stream>>>(
        PHI, nullptr, 1024, 0, 1024, pmW2T, 1024, pm_b2, nullptr, PMbuf, 65536, 128, 1024, 1024);
    gemm128<EPI_BF16_RELU><<<dim3(8, 512, 1), 256, 0, stream>>>(
        HS, nullptr, 1024, 0, 1024, psW1T, 1024, ps_b1, PHI, nullptr, 65536, 1024, 1024, 1024);
    gemm128<EPI_F32_SP><<<dim3(1, 512, 1), 256, 0, stream>>>(
        PHI, nullptr, 1024, 0, 1024, psW2T, 1024, ps_b2, nullptr, PSbuf, 65536, 128, 1024, 1024);
    gemm128<EPI_BF16_RELU><<<dim3(8, 512, 1), 256, 0, stream>>>(
        HS, ZBF, 1024, 128, 1024, dmW1T, 1152, dm_b1, PHI, nullptr, 65536, 1024, 1152, 1152);
    gemm128<EPI_F32_SIG><<<dim3(4, 512, 1), 256, 0, stream>>>(
        PHI, nullptr, 1024, 0, 1024, dmW2T, 1024, dm_b2, nullptr, out + O_XM, 65536, 512, 1024, 1024);

    loss_per_t<<<256, 256, 0, stream>>>(x, out + O_XM, out + O_MU, out + O_STD,
                                        PMbuf, PSbuf, kldT, nllT);
    loss_final<<<1, 256, 0, stream>>>(kldT, nllT, out);
}

// Round 16
// 17580.016 us; speedup vs baseline: 3.0197x; 1.2138x over previous
//
#include <hip/hip_runtime.h>

typedef unsigned short u16;
typedef __bf16 bf16x8 __attribute__((ext_vector_type(8)));
typedef float f32x4 __attribute__((ext_vector_type(4)));
typedef unsigned uint32x4 __attribute__((ext_vector_type(4)));

#define EPSC 1e-6f

// ---------- helpers ----------
__device__ __forceinline__ float b2f(u16 x) { return __uint_as_float(((unsigned)x) << 16); }
__device__ __forceinline__ u16 f2b(float f) {
    unsigned u = __float_as_uint(f);
    unsigned r = (u + 0x7fffu + ((u >> 16) & 1u)) >> 16;
    return (u16)r;
}
__device__ __forceinline__ float softplusf(float x) {
    return fmaxf(x, 0.f) + log1pf(__expf(-fabsf(x)));
}

// ---------- conversion / transpose kernels ----------
__global__ void conv_x4(u16* __restrict__ dst, const float* __restrict__ x) {
    size_t i4 = (size_t)blockIdx.x * 256 + threadIdx.x;
    size_t o = i4 * 4;
    int d = (int)(o & 511);
    int b = (int)((o >> 9) & 255);
    int t = (int)(o >> 17);
    float4 v = *(const float4*)(x + ((size_t)b * 256 + t) * 512 + d);
    unsigned p0 = (unsigned)f2b(v.x) | ((unsigned)f2b(v.y) << 16);
    unsigned p1 = (unsigned)f2b(v.z) | ((unsigned)f2b(v.w) << 16);
    *(uint2*)(dst + o) = make_uint2(p0, p1);
}

__global__ void conv_f32_bf16(u16* __restrict__ dst, const float* __restrict__ src, int n) {
    int i = blockIdx.x * 256 + threadIdx.x;
    if (i < n) dst[i] = f2b(src[i]);
}

__global__ void tr_conv(u16* __restrict__ dst, const float* __restrict__ src,
                        int R, int C, int ld) {
    int idx = blockIdx.x * 256 + threadIdx.x;
    if (idx >= R * C) return;
    int c = idx / R, r = idx % R;
    dst[idx] = f2b(src[(size_t)r * ld + c]);
}

// MFMA B-frag layouts (verified rounds 14/15): contiguous 1KB wave-wide frag reads.
__global__ void conv_fragB(u16* __restrict__ dst, const float* __restrict__ em1,
                           const float* __restrict__ es1) {
    int idx = blockIdx.x * 256 + threadIdx.x;       // 524288 threads
    int col = idx >> 8, kb = idx & 255;
    int k = kb * 8, ct = col >> 4, lr = col & 15, kq = kb >> 2, lk = kb & 3;
    size_t off = ((size_t)ct * 64 + kq) * 512 + lk * 128 + lr * 8;
    const float* src = (col < 1024) ? em1 : es1;
    const int c = (col < 1024) ? col : col - 1024;
#pragma unroll
    for (int j = 0; j < 8; j++)
        dst[off + j] = f2b(src[(size_t)(k + j) * 1024 + c]);
}

__global__ void conv_fragB2(u16* __restrict__ dst, const float* __restrict__ src) {
    int idx = blockIdx.x * 256 + threadIdx.x;       // 16384 threads
    int col = idx >> 7, kb = idx & 127;
    int k = kb * 8, ct = col >> 4, lr = col & 15, kq = kb >> 2, lk = kb & 3;
    size_t off = ((size_t)ct * 32 + kq) * 512 + lk * 128 + lr * 8;
#pragma unroll
    for (int j = 0; j < 8; j++)
        dst[off + j] = f2b(src[(size_t)(k + j) * 128 + col]);
}

__global__ void conv_fragG(u16* __restrict__ dst, const float* __restrict__ gwih) {
    int idx = blockIdx.x * 256 + threadIdx.x;       // 49152 threads
    int gate = idx >> 14, rem = idx & 16383;
    int col = rem >> 4, kb = rem & 15;
    int k = kb * 8, ct = col >> 4, lr = col & 15, kq = kb >> 2, lk = kb & 3;
    size_t off = (size_t)gate * 131072 + ((size_t)ct * 4 + kq) * 512 + lk * 128 + lr * 8;
#pragma unroll
    for (int j = 0; j < 8; j++)
        dst[off + j] = f2b(gwih[(size_t)(1024 + k + j) * 3072 + gate * 1024 + col]);
}

// ---------- generic 128x128 bf16 MFMA GEMM (phase A/C) ----------
enum { EPI_PARTIAL = 0, EPI_BF16_RELU = 1, EPI_BF16_NONE = 2,
       EPI_F32_RELU = 3, EPI_F32_SP = 4, EPI_F32_SIG = 5, EPI_TGIP = 6 };

template <int EPI>
__global__ __launch_bounds__(256)
void gemm128(const u16* __restrict__ A0, const u16* __restrict__ A1,
             int lda0, int lda1, int kSplit,
             const u16* __restrict__ Wt, int ldw,
             const float* __restrict__ bias,
             u16* __restrict__ Cb, float* __restrict__ Cf,
             int M, int N, int K, int kChunk) {
    __shared__ __align__(16) u16 As[128 * 72];
    __shared__ __align__(16) u16 Bs[128 * 72];
    const int tid = threadIdx.x;
    const int wid = tid >> 6, lane = tid & 63;
    const int wm = wid >> 1, wn = wid & 1;
    const int lr = lane & 15, lk = lane >> 4;
    const int m0 = blockIdx.y * 128, n0 = blockIdx.x * 128;
    const int kBeg = blockIdx.z * kChunk;
    const int rsub = lane >> 3;
    const int csub = (lane & 7) * 8;

    f32x4 acc[4][4];
#pragma unroll
    for (int i = 0; i < 4; i++)
#pragma unroll
        for (int j = 0; j < 4; j++) { f32x4 z = {0.f, 0.f, 0.f, 0.f}; acc[i][j] = z; }

    for (int kt = 0; kt < kChunk; kt += 64) {
        const int k0 = kBeg + kt;
        const u16* Ap; int kk, lda;
        if (k0 < kSplit) { Ap = A0; kk = k0; lda = lda0; }
        else             { Ap = A1; kk = k0 - kSplit; lda = lda1; }
        uint4 ra[4], rb[4];
#pragma unroll
        for (int i = 0; i < 4; i++) {
            const int q = wid * 4 + i;
            const int r = q * 8 + rsub;
            ra[i] = *(const uint4*)(Ap + (size_t)(m0 + r) * lda + kk + csub);
            rb[i] = *(const uint4*)(Wt + (size_t)(n0 + r) * ldw + k0 + csub);
        }
        __syncthreads();
#pragma unroll
        for (int i = 0; i < 4; i++) {
            const int q = wid * 4 + i;
            const int r = q * 8 + rsub;
            *(uint4*)&As[r * 72 + csub] = ra[i];
            *(uint4*)&Bs[r * 72 + csub] = rb[i];
        }
        __syncthreads();
#pragma unroll
        for (int s = 0; s < 2; s++) {
            bf16x8 af[4], bfr[4];
#pragma unroll
            for (int i = 0; i < 4; i++)
                af[i] = *(const bf16x8*)&As[(wm * 64 + i * 16 + lr) * 72 + s * 32 + lk * 8];
#pragma unroll
            for (int j = 0; j < 4; j++)
                bfr[j] = *(const bf16x8*)&Bs[(wn * 64 + j * 16 + lr) * 72 + s * 32 + lk * 8];
#pragma unroll
            for (int i = 0; i < 4; i++)
#pragma unroll
                for (int j = 0; j < 4; j++)
                    acc[i][j] = __builtin_amdgcn_mfma_f32_16x16x32_bf16(af[i], bfr[j], acc[i][j], 0, 0, 0);
        }
    }

    const int rowb = m0 + wm * 64, colb = n0 + wn * 64;
#pragma unroll
    for (int i = 0; i < 4; i++) {
#pragma unroll
        for (int j = 0; j < 4; j++) {
            const int col = colb + j * 16 + lr;
            if (EPI == EPI_TGIP) {
                const int row0 = rowb + i * 16 + lk * 4;
                const int tt = row0 >> 8, b0 = row0 & 255;
                const int gate = col >> 10, cc = col & 1023;
                unsigned lo = (unsigned)f2b(acc[i][j][0]) | ((unsigned)f2b(acc[i][j][1]) << 16);
                unsigned hi = (unsigned)f2b(acc[i][j][2]) | ((unsigned)f2b(acc[i][j][3]) << 16);
                *(uint2*)(Cb + (((size_t)tt * 3 + gate) * 1024 + cc) * 256 + b0) = make_uint2(lo, hi);
            } else {
#pragma unroll
                for (int r = 0; r < 4; r++) {
                    const int row = rowb + i * 16 + lk * 4 + r;
                    float v = acc[i][j][r];
                    if (EPI == EPI_PARTIAL) {
                        Cf[(size_t)blockIdx.z * ((size_t)M * N) + (size_t)row * N + col] = v;
                    } else {
                        if (bias) v += bias[col];
                        if (EPI == EPI_BF16_RELU || EPI == EPI_F32_RELU) v = fmaxf(v, 0.f);
                        else if (EPI == EPI_F32_SP)  v = softplusf(v);
                        else if (EPI == EPI_F32_SIG) v = 1.f / (1.f + __expf(-v));
                        if (EPI == EPI_BF16_RELU || EPI == EPI_BF16_NONE) Cb[(size_t)row * N + col] = f2b(v);
                        else Cf[(size_t)row * N + col] = v;
                    }
                }
            }
        }
    }
}

// ---------- workspace layout (bytes) ----------
static constexpr size_t oPHIXWT  = 0;
static constexpr size_t oWCATT   = 1048576;                // wcatF frag (8 MB)
static constexpr size_t oEMW2T   = 9437184;                // em2F
static constexpr size_t oESW2T   = 9699328;                // es2F
static constexpr size_t oWIHPHIT = 9961472;
static constexpr size_t oWIHZT   = 16252928;               // wihZF
static constexpr size_t oPMW1T   = 17039360;
static constexpr size_t oPMW2T   = 19136512;
static constexpr size_t oPSW1T   = 19398656;
static constexpr size_t oPSW2T   = 21495808;
static constexpr size_t oDMW1T   = 21757952;
static constexpr size_t oDMW2T   = 24117248;
static constexpr size_t oHS      = 25165824;               // [T+1][B][H] bf16
static constexpr size_t oZBF     = 159907840;              // [T][B][Z] bf16
static constexpr size_t oT12     = 176685056;              // [256][2048] bf16 (single buffer)
static constexpr size_t oBAR     = 177733632;
static constexpr size_t oKLDT    = 177737728;
static constexpr size_t oNLLT    = 177738752;
static constexpr size_t oPHI     = 177739776;              // [65536][1024] bf16
static constexpr size_t oGIP     = 311957504;              // GIPT [256][3][1024][256] bf16
static constexpr size_t WS_NEED  = 714610688;

static constexpr size_t NZ = (size_t)256 * 256 * 128;
static constexpr size_t O_Z  = 3;
static constexpr size_t O_MU = 3 + NZ;
static constexpr size_t O_STD = 3 + 2 * NZ;
static constexpr size_t O_XM = 3 + 3 * NZ;

// ---------- K1: W1 partitioned, no redundancy ----------
// 256 blocks. n = 2*(bx&7)+(bx>>7) (XCD sees only 2 wcat slabs = 1MB, L2-hot),
// g = (bx>>3)&15. Block computes T12(t)[16g..+15][128n..+127] from h(t),phi(t)
// (global, kernel-boundary coherent). Plain memory ops only.
__global__ __launch_bounds__(256, 1)
void vrnn_w1(int t, const float* __restrict__ em_b1, const float* __restrict__ es_b1,
             char* ws) {
    __shared__ __align__(16) u16 hL[16 * 1032];
    __shared__ __align__(16) u16 PH[16 * 1032];
    __shared__ __align__(16) u16 TH16[16 * 136];

    const int bx = blockIdx.x, tid = threadIdx.x;
    const int wid = tid >> 6, lane = tid & 63;
    const int lr = lane & 15, lk = lane >> 4;
    const int n = 2 * (bx & 7) + (bx >> 7);
    const int g = (bx >> 3) & 15;
    const int r0 = g * 16;

    const u16* wcatF = (const u16*)(ws + oWCATT);
    const u16* PHI   = (const u16*)(ws + oPHI);
    const u16* HS    = (const u16*)(ws + oHS);
    u16* T12g = (u16*)(ws + oT12);

    const int srow = tid >> 4, sc8 = (tid & 15) * 8;

    // stage h(t) and phi(t) rows
    {
        const u16* hs = HS + (size_t)t * 262144 + (size_t)(r0 + srow) * 1024 + sc8;
        const u16* ps = PHI + (size_t)t * 262144 + (size_t)(r0 + srow) * 1024 + sc8;
#pragma unroll
        for (int p = 0; p < 8; p++) {
            *(uint32x4*)&hL[srow * 1032 + sc8 + p * 128] = *(const uint32x4*)(hs + p * 128);
            *(uint32x4*)&PH[srow * 1032 + sc8 + p * 128] = *(const uint32x4*)(ps + p * 128);
        }
    }
    __syncthreads();

    f32x4 a0 = {0.f,0.f,0.f,0.f}, a1 = {0.f,0.f,0.f,0.f};
    const int ct0 = n * 8 + wid * 2;
    const u16* b0s = wcatF + (size_t)ct0 * 32768 + lk * 128 + lr * 8;
    const u16* b1s = b0s + 32768;
#pragma unroll 1
    for (int kq = 0; kq < 32; kq++) {                // h half
        bf16x8 af = *(const bf16x8*)&hL[lr * 1032 + kq * 32 + lk * 8];
        a0 = __builtin_amdgcn_mfma_f32_16x16x32_bf16(af, *(const bf16x8*)(b0s + (size_t)kq * 512), a0, 0, 0, 0);
        a1 = __builtin_amdgcn_mfma_f32_16x16x32_bf16(af, *(const bf16x8*)(b1s + (size_t)kq * 512), a1, 0, 0, 0);
    }
#pragma unroll 1
    for (int kq = 32; kq < 64; kq++) {               // phi half
        bf16x8 af = *(const bf16x8*)&PH[lr * 1032 + (kq - 32) * 32 + lk * 8];
        a0 = __builtin_amdgcn_mfma_f32_16x16x32_bf16(af, *(const bf16x8*)(b0s + (size_t)kq * 512), a0, 0, 0, 0);
        a1 = __builtin_amdgcn_mfma_f32_16x16x32_bf16(af, *(const bf16x8*)(b1s + (size_t)kq * 512), a1, 0, 0, 0);
    }
    __syncthreads();
    // epilogue: bias+relu -> LDS repack -> coalesced T12 store
#pragma unroll
    for (int i = 0; i < 2; i++) {
        const f32x4 a = i ? a1 : a0;
        const int lct = wid * 2 + i;
        const int colg = n * 128 + lct * 16 + lr;
        const float bb = (colg < 1024) ? em_b1[colg] : es_b1[colg - 1024];
#pragma unroll
        for (int r = 0; r < 4; r++)
            TH16[(lk * 4 + r) * 136 + lct * 16 + lr] = f2b(fmaxf(a[r] + bb, 0.f));
    }
    __syncthreads();
    *(uint32x4*)(T12g + (size_t)(r0 + srow) * 2048 + n * 128 + sc8) =
        *(const uint32x4*)&TH16[srow * 136 + sc8];
}

// ---------- K2: z + GRU, GRU partitioned by columns ----------
// 64 blocks: q = bx&3 (constant per XCD -> wihZ slice L2-hot), g = bx>>2.
// Stage T12 row-set; zm/zs redundant x4; z; GRU cols q*256..; h-slice + outputs.
__global__ __launch_bounds__(256, 1)
void vrnn_w23(int t,
              const float* __restrict__ eps,
              const float* __restrict__ em_b2, const float* __restrict__ es_b2,
              const float* __restrict__ gbih, const float* __restrict__ gbhh,
              char* ws, float* out) {
    __shared__ __align__(16) u16 S12[16 * 2056];    // T12 rows; hT aliases after zm/zs
    __shared__ float zmL[2048], zsL[2048];
    __shared__ __align__(16) u16 zTH[16 * 136];

    const int bx = blockIdx.x, tid = threadIdx.x;
    const int wid = tid >> 6, lane = tid & 63;
    const int lr = lane & 15, lk = lane >> 4;
    const int q = bx & 3, g = bx >> 2;
    const int r0 = g * 16;

    const u16* em2F  = (const u16*)(ws + oEMW2T);
    const u16* es2F  = (const u16*)(ws + oESW2T);
    const u16* wihZF = (const u16*)(ws + oWIHZT);
    const u16* GIPT  = (const u16*)(ws + oGIP);
    u16* HS   = (u16*)(ws + oHS);
    u16* ZBFg = (u16*)(ws + oZBF);
    u16* T12g = (u16*)(ws + oT12);

    float* outZ  = out + O_Z;
    float* outMu = out + O_MU;
    float* outSd = out + O_STD;

    u16* hT = S12;                   // [16][264+] after S12 dead

    const int srow = tid >> 4, sc8 = (tid & 15) * 8;

    // ---- stage T12(t) ----
    {
        const u16* src = T12g + (size_t)(r0 + srow) * 2048 + sc8;
#pragma unroll
        for (int p = 0; p < 16; p++)
            *(uint32x4*)&S12[srow * 2056 + sc8 + p * 128] = *(const uint32x4*)(src + p * 128);
    }
    __syncthreads();

    // ---- zm/zs (redundant x4; frag-stream W2) ----
    {
        const int halfz = wid >> 1, cq = wid & 1;
        const u16* WF = (halfz ? es2F : em2F) + (size_t)(cq * 4) * 16384 + lk * 128 + lr * 8;
        const u16* Sr = &S12[lr * 2056 + halfz * 1024];
        f32x4 az0 = {0.f,0.f,0.f,0.f}, az1 = az0, az2 = az0, az3 = az0;
#pragma unroll 1
        for (int kq = 0; kq < 32; kq++) {
            bf16x8 af = *(const bf16x8*)(Sr + kq * 32 + lk * 8);
            az0 = __builtin_amdgcn_mfma_f32_16x16x32_bf16(af, *(const bf16x8*)(WF + (size_t)kq * 512), az0, 0, 0, 0);
            az1 = __builtin_amdgcn_mfma_f32_16x16x32_bf16(af, *(const bf16x8*)(WF + 16384 + (size_t)kq * 512), az1, 0, 0, 0);
            az2 = __builtin_amdgcn_mfma_f32_16x16x32_bf16(af, *(const bf16x8*)(WF + 32768 + (size_t)kq * 512), az2, 0, 0, 0);
            az3 = __builtin_amdgcn_mfma_f32_16x16x32_bf16(af, *(const bf16x8*)(WF + 49152 + (size_t)kq * 512), az3, 0, 0, 0);
        }
#pragma unroll
        for (int p = 0; p < 4; p++) {
            const f32x4 az = (p == 0) ? az0 : (p == 1) ? az1 : (p == 2) ? az2 : az3;
            const int c = cq * 64 + p * 16 + lr;
#pragma unroll
            for (int r = 0; r < 4; r++) {
                const int row = lk * 4 + r;
                if (!halfz) zmL[row * 128 + c] = fmaxf(az[r] + em_b2[c], 0.f);
                else        zsL[row * 128 + c] = softplusf(az[r] + es_b2[c]);
            }
        }
    }
    __syncthreads();

    // ---- z = zm + zs*eps -> zTH; q==0 writes outputs ----
    {
        const int row = tid >> 4, col = (tid & 15) * 8;
        const size_t o = (size_t)t * 32768 + (size_t)(r0 + row) * 128 + col;
        const float* ep = eps + o;
        float4 e0 = *(const float4*)ep, e1 = *(const float4*)(ep + 4);
        float zmv[8], zsv[8], zv[8];
#pragma unroll
        for (int i = 0; i < 8; i++) {
            zmv[i] = zmL[row * 128 + col + i];
            zsv[i] = zsL[row * 128 + col + i];
            const float ev = (i < 4) ? (&e0.x)[i] : (&e1.x)[i - 4];
            zv[i] = zmv[i] + zsv[i] * ev;
        }
        uint32x4 zp;
#pragma unroll
        for (int j = 0; j < 4; j++)
            zp[j] = (unsigned)f2b(zv[2 * j]) | ((unsigned)f2b(zv[2 * j + 1]) << 16);
        *(uint32x4*)&zTH[row * 136 + col] = zp;
        if (q == 0) {
#pragma unroll
            for (int i = 0; i < 8; i++) {
                outMu[o + i] = zmv[i];
                outSd[o + i] = zsv[i];
                outZ[o + i]  = zv[i];
            }
            *(uint32x4*)(ZBFg + o) = zp;
        }
    }
    __syncthreads();

    // ---- GRU for cols q*256..q*256+255 (16 col-tiles; 4 per wave) ----
    {
        bf16x8 zf0 = *(const bf16x8*)&zTH[lr * 136 + lk * 8];
        bf16x8 zf1 = *(const bf16x8*)&zTH[lr * 136 + 32 + lk * 8];
        bf16x8 zf2 = *(const bf16x8*)&zTH[lr * 136 + 64 + lk * 8];
        bf16x8 zf3 = *(const bf16x8*)&zTH[lr * 136 + 96 + lk * 8];
        const u16* gT = GIPT + (size_t)t * 786432;
        u16 hout[4][4];   // [i][r]
#pragma unroll 1
        for (int i = 0; i < 4; i++) {
            const int ct = q * 16 + wid * 4 + i;
            const int col = ct * 16 + lr;
            const u16* bR = wihZF + (size_t)ct * 2048 + lk * 128 + lr * 8;
            const u16* bU = bR + 131072;
            const u16* bN = bU + 131072;
            f32x4 aR = {0.f,0.f,0.f,0.f}, aU = aR, aN = aR;
            aR = __builtin_amdgcn_mfma_f32_16x16x32_bf16(zf0, *(const bf16x8*)(bR), aR, 0, 0, 0);
            aR = __builtin_amdgcn_mfma_f32_16x16x32_bf16(zf1, *(const bf16x8*)(bR + 512), aR, 0, 0, 0);
            aR = __builtin_amdgcn_mfma_f32_16x16x32_bf16(zf2, *(const bf16x8*)(bR + 1024), aR, 0, 0, 0);
            aR = __builtin_amdgcn_mfma_f32_16x16x32_bf16(zf3, *(const bf16x8*)(bR + 1536), aR, 0, 0, 0);
            aU = __builtin_amdgcn_mfma_f32_16x16x32_bf16(zf0, *(const bf16x8*)(bU), aU, 0, 0, 0);
            aU = __builtin_amdgcn_mfma_f32_16x16x32_bf16(zf1, *(const bf16x8*)(bU + 512), aU, 0, 0, 0);
            aU = __builtin_amdgcn_mfma_f32_16x16x32_bf16(zf2, *(const bf16x8*)(bU + 1024), aU, 0, 0, 0);
            aU = __builtin_amdgcn_mfma_f32_16x16x32_bf16(zf3, *(const bf16x8*)(bU + 1536), aU, 0, 0, 0);
            aN = __builtin_amdgcn_mfma_f32_16x16x32_bf16(zf0, *(const bf16x8*)(bN), aN, 0, 0, 0);
            aN = __builtin_amdgcn_mfma_f32_16x16x32_bf16(zf1, *(const bf16x8*)(bN + 512), aN, 0, 0, 0);
            aN = __builtin_amdgcn_mfma_f32_16x16x32_bf16(zf2, *(const bf16x8*)(bN + 1024), aN, 0, 0, 0);
            aN = __builtin_amdgcn_mfma_f32_16x16x32_bf16(zf3, *(const bf16x8*)(bN + 1536), aN, 0, 0, 0);
            const size_t gb = (size_t)col * 256 + r0 + lk * 4;
            uint2 gR2 = *(const uint2*)(gT + gb);
            uint2 gU2 = *(const uint2*)(gT + 262144 + gb);
            uint2 gN2 = *(const uint2*)(gT + 524288 + gb);
            const u16 gRv[4] = {(u16)(gR2.x & 0xffff), (u16)(gR2.x >> 16),
                                (u16)(gR2.y & 0xffff), (u16)(gR2.y >> 16)};
            const u16 gUv[4] = {(u16)(gU2.x & 0xffff), (u16)(gU2.x >> 16),
                                (u16)(gU2.y & 0xffff), (u16)(gU2.y >> 16)};
            const u16 gNv[4] = {(u16)(gN2.x & 0xffff), (u16)(gN2.x >> 16),
                                (u16)(gN2.y & 0xffff), (u16)(gN2.y >> 16)};
            const float bihR = gbih[col],        bhR = gbhh[col];
            const float bihU = gbih[1024 + col], bhU = gbhh[1024 + col];
            const float bihN = gbih[2048 + col], bhN = gbhh[2048 + col];
#pragma unroll
            for (int r = 0; r < 4; r++) {
                const float gr = aR[r] + b2f(gRv[r]) + bihR + bhR;
                const float gu = aU[r] + b2f(gUv[r]) + bihU + bhU;
                float gn       = aN[r] + b2f(gNv[r]) + bihN;
                const float rr_ = 1.f / (1.f + __expf(-gr));
                const float uu  = 1.f / (1.f + __expf(-gu));
                gn += rr_ * bhN;
                const float e2 = __expf(-2.f * fabsf(gn));
                float th = (1.f - e2) / (1.f + e2);
                th = (gn < 0.f) ? -th : th;
                hout[i][r] = f2b((1.f - uu) * th);
            }
        }
        __syncthreads();   // S12 dead -> hT
#pragma unroll
        for (int i = 0; i < 4; i++) {
            const int lct = wid * 4 + i;
#pragma unroll
            for (int r = 0; r < 4; r++)
                hT[(lk * 4 + r) * 264 + lct * 16 + lr] = hout[i][r];
        }
    }
    __syncthreads();

    // ---- h(t+1) slice -> HS (coalesced 16B stores) ----
    {
        const int row = tid >> 4, c16 = (tid & 15) * 16;
        u16* dst = HS + (size_t)(t + 1) * 262144 + (size_t)(r0 + row) * 1024 + q * 256 + c16;
        *(uint32x4*)dst       = *(const uint32x4*)&hT[row * 264 + c16];
        *(uint32x4*)(dst + 8) = *(const uint32x4*)&hT[row * 264 + c16 + 8];
    }
}

// ---------- loss ----------
__global__ __launch_bounds__(256)
void loss_per_t(const float* __restrict__ x,
                const float* __restrict__ xm,
                const float* __restrict__ zm, const float* __restrict__ zs,
                const float* __restrict__ pm, const float* __restrict__ ps,
                float* __restrict__ kldT, float* __restrict__ nllT) {
    const int t = blockIdx.x, bb = threadIdx.x;
    float kld = 0.f, nll = 0.f;
    const size_t ozb = ((size_t)t * 256 + bb) * 128;
    for (int zz = 0; zz < 128; zz++) {
        const float qs = zs[ozb + zz], qm = zm[ozb + zz];
        const float pmv = pm[ozb + zz], psv = ps[ozb + zz];
        const float d = qm - pmv;
        kld += logf(psv + EPSC) - logf(qs + EPSC)
             + (qs * qs + d * d) / (2.f * psv * psv + EPSC) - 0.5f;
    }
    const size_t oxb = ((size_t)t * 256 + bb) * 512;
    const size_t oxi = ((size_t)bb * 256 + t) * 512;
    for (int dd = 0; dd < 512; dd++) {
        const float xv = x[oxi + dd];
        float m = xm[oxb + dd];
        m = fminf(fmaxf(m, 1e-6f), 1.f - 1e-6f);
        nll -= xv * logf(m) + (1.f - xv) * log1pf(-m);
    }
    __shared__ float sk[256], sn[256];
    sk[bb] = kld; sn[bb] = nll;
    __syncthreads();
    for (int s = 128; s > 0; s >>= 1) {
        if (bb < s) { sk[bb] += sk[bb + s]; sn[bb] += sn[bb + s]; }
        __syncthreads();
    }
    if (bb == 0) { kldT[t] = sk[0] / 256.f; nllT[t] = sn[0] / 256.f; }
}

__global__ __launch_bounds__(256)
void loss_final(const float* __restrict__ kldT, const float* __restrict__ nllT,
                float* __restrict__ out) {
    const int tid = threadIdx.x;
    __shared__ float s[256];
    s[tid] = kldT[tid] + nllT[tid];
    __syncthreads();
    for (int st = 128; st > 0; st >>= 1) {
        if (tid < st) s[tid] += s[tid + st];
        __syncthreads();
    }
    if (tid == 0) { out[0] = s[0]; out[1] = kldT[255]; out[2] = nllT[255]; }
}

extern "C" void kernel_launch(void* const* d_in, const int* in_sizes, int n_in,
                              void* d_out, int out_size, void* d_ws, size_t ws_size,
                              hipStream_t stream) {
    const float* x      = (const float*)d_in[0];
    const float* eps    = (const float*)d_in[1];
    const float* h0     = (const float*)d_in[2];
    const float* phix_w = (const float*)d_in[3];
    const float* phix_b = (const float*)d_in[4];
    const float* pm_w1  = (const float*)d_in[5];
    const float* pm_b1  = (const float*)d_in[6];
    const float* pm_w2  = (const float*)d_in[7];
    const float* pm_b2  = (const float*)d_in[8];
    const float* ps_w1  = (const float*)d_in[9];
    const float* ps_b1  = (const float*)d_in[10];
    const float* ps_w2  = (const float*)d_in[11];
    const float* ps_b2  = (const float*)d_in[12];
    const float* em_w1  = (const float*)d_in[13];
    const float* em_b1  = (const float*)d_in[14];
    const float* em_w2  = (const float*)d_in[15];
    const float* em_b2  = (const float*)d_in[16];
    const float* es_w1  = (const float*)d_in[17];
    const float* es_b1  = (const float*)d_in[18];
    const float* es_w2  = (const float*)d_in[19];
    const float* es_b2  = (const float*)d_in[20];
    const float* dm_w1  = (const float*)d_in[21];
    const float* dm_b1  = (const float*)d_in[22];
    const float* dm_w2  = (const float*)d_in[23];
    const float* dm_b2  = (const float*)d_in[24];
    const float* gwih   = (const float*)d_in[25];
    const float* gbih   = (const float*)d_in[26];
    const float* gbhh   = (const float*)d_in[27];
    float* out = (float*)d_out;

    if (ws_size < WS_NEED) return;
    char* w = (char*)d_ws;
    u16* phixWt  = (u16*)(w + oPHIXWT);
    u16* wcatF   = (u16*)(w + oWCATT);
    u16* em2F    = (u16*)(w + oEMW2T);
    u16* es2F    = (u16*)(w + oESW2T);
    u16* wihPhiT = (u16*)(w + oWIHPHIT);
    u16* wihZF   = (u16*)(w + oWIHZT);
    u16* pmW1T   = (u16*)(w + oPMW1T);
    u16* pmW2T   = (u16*)(w + oPMW2T);
    u16* psW1T   = (u16*)(w + oPSW1T);
    u16* psW2T   = (u16*)(w + oPSW2T);
    u16* dmW1T   = (u16*)(w + oDMW1T);
    u16* dmW2T   = (u16*)(w + oDMW2T);
    u16* HS      = (u16*)(w + oHS);
    u16* ZBF     = (u16*)(w + oZBF);
    u16* PHI     = (u16*)(w + oPHI);
    u16* GIPT    = (u16*)(w + oGIP);
    u16* XbfT    = (u16*)(w + oGIP);                 // dead after phi GEMM
    float* PMbuf = (float*)(w + oGIP);               // phase C only (GIPT dead)
    float* PSbuf = (float*)(w + oGIP + 33554432);
    float* kldT  = (float*)(w + oKLDT);
    float* nllT  = (float*)(w + oNLLT);

    // ---- phase A ----
    conv_x4<<<32768, 256, 0, stream>>>(XbfT, x);
    conv_f32_bf16<<<1024, 256, 0, stream>>>(HS, h0, 262144);
    tr_conv<<<2048, 256, 0, stream>>>(phixWt, phix_w, 512, 1024, 1024);
    conv_fragB<<<2048, 256, 0, stream>>>(wcatF, em_w1, es_w1);
    conv_fragB2<<<64, 256, 0, stream>>>(em2F, em_w2);
    conv_fragB2<<<64, 256, 0, stream>>>(es2F, es_w2);
    tr_conv<<<12288, 256, 0, stream>>>(wihPhiT, gwih, 1024, 3072, 3072);
    conv_fragG<<<192, 256, 0, stream>>>(wihZF, gwih);
    tr_conv<<<4096, 256, 0, stream>>>(pmW1T, pm_w1, 1024, 1024, 1024);
    tr_conv<<<512, 256, 0, stream>>>(pmW2T, pm_w2, 1024, 128, 128);
    tr_conv<<<4096, 256, 0, stream>>>(psW1T, ps_w1, 1024, 1024, 1024);
    tr_conv<<<512, 256, 0, stream>>>(psW2T, ps_w2, 1024, 128, 128);
    tr_conv<<<4608, 256, 0, stream>>>(dmW1T, dm_w1, 1152, 1024, 1024);
    tr_conv<<<2048, 256, 0, stream>>>(dmW2T, dm_w2, 1024, 512, 512);

    gemm128<EPI_BF16_RELU><<<dim3(8, 512, 1), 256, 0, stream>>>(
        XbfT, nullptr, 512, 0, 512, phixWt, 512, phix_b, PHI, nullptr, 65536, 1024, 512, 512);
    gemm128<EPI_TGIP><<<dim3(24, 512, 1), 256, 0, stream>>>(
        PHI, nullptr, 1024, 0, 1024, wihPhiT, 1024, nullptr, GIPT, nullptr, 65536, 3072, 1024, 1024);

    // ---- phase B: 512 step launches (kernel boundary = sync; zero redundancy) ----
    for (int t = 0; t < 256; t++) {
        vrnn_w1<<<256, 256, 0, stream>>>(t, em_b1, es_b1, (char*)d_ws);
        vrnn_w23<<<64, 256, 0, stream>>>(t, eps, em_b2, es_b2, gbih, gbhh,
                                         (char*)d_ws, out);
    }

    // ---- phase C ----
    gemm128<EPI_BF16_RELU><<<dim3(8, 512, 1), 256, 0, stream>>>(
        HS, nullptr, 1024, 0, 1024, pmW1T, 1024, pm_b1, PHI, nullptr, 65536, 1024, 1024, 1024);
    gemm128<EPI_F32_RELU><<<dim3(1, 512, 1), 256, 0, stream>>>(
        PHI, nullptr, 1024, 0, 1024, pmW2T, 1024, pm_b2, nullptr, PMbuf, 65536, 128, 1024, 1024);
    gemm128<EPI_BF16_RELU><<<dim3(8, 512, 1), 256, 0, stream>>>(
        HS, nullptr, 1024, 0, 1024, psW1T, 1024, ps_b1, PHI, nullptr, 65536, 1024, 1024, 1024);
    gemm128<EPI_F32_SP><<<dim3(1, 512, 1), 256, 0, stream>>>(
        PHI, nullptr, 1024, 0, 1024, psW2T, 1024, ps_b2, nullptr, PSbuf, 65536, 128, 1024, 1024);
    gemm128<EPI_BF16_RELU><<<dim3(8, 512, 1), 256, 0, stream>>>(
        HS, ZBF, 1024, 128, 1024, dmW1T, 1152, dm_b1, PHI, nullptr, 65536, 1024, 1152, 1152);
    gemm128<EPI_F32_SIG><<<dim3(4, 512, 1), 256, 0, stream>>>(
        PHI, nullptr, 1024, 0, 1024, dmW2T, 1024, dm_b2, nullptr, out + O_XM, 65536, 512, 1024, 1024);

    loss_per_t<<<256, 256, 0, stream>>>(x, out + O_XM, out + O_MU, out + O_STD,
                                        PMbuf, PSbuf, kldT, nllT);
    loss_final<<<1, 256, 0, stream>>>(kldT, nllT, out);
}